// Round 9
// baseline (395.645 us; speedup 1.0000x reference)
//
#include <hip/hip_runtime.h>
#include <math.h>

#define SEQ 2048
#define DMODEL 1024
#define DIN 2048
#define NST 16
#define DTR 64
#define CH 32
#define NCH (SEQ / CH)
#define LOG2E 1.4426950408889634f

typedef __attribute__((ext_vector_type(8))) _Float16 f16x8;
typedef __attribute__((ext_vector_type(4))) float f32x4;

// f16 split (11-bit mantissa): hi = f16(v), lo = f16((v-hi)*2048).
// hi + lo*2^-11 reconstructs to ~2^-22 relative: NOT a precision cut.
__device__ __forceinline__ ushort f2h(float f) {
  union { _Float16 h; ushort u; } c; c.h = (_Float16)f; return c.u;
}
__device__ __forceinline__ float h2f(ushort u) {
  union { ushort u; _Float16 h; } c; c.u = u; return (float)c.h;
}
__device__ __forceinline__ ushort2 split2(float v) {
  ushort hh = f2h(v);
  return make_ushort2(hh, f2h((v - h2f(hh)) * 2048.f));
}
__device__ __forceinline__ float join2(ushort2 p) {
  return h2f(p.x) + h2f(p.y) * (1.f / 2048.f);
}
__device__ __forceinline__ float splus(float v) {
  return v > 20.f ? v : log1pf(__expf(v));
}
// p[n] = e^(n+1), depth-4 mul tree (no transcendentals).
__device__ __forceinline__ void powers16(float e, float* p) {
  float e2 = e * e, e4 = e2 * e2, e8 = e4 * e4;
  p[0] = e;       p[1] = e2;       p[2] = e2 * e;   p[3] = e4;
  p[4] = e4 * e;  p[5] = e4 * e2;  p[6] = e4 * p[2]; p[7] = e8;
  p[8] = e8 * e;  p[9] = e8 * e2;  p[10] = e8 * p[2]; p[11] = e8 * e4;
  p[12] = e8 * p[4]; p[13] = e8 * p[5]; p[14] = e8 * p[6]; p[15] = e8 * e8;
}

#define GLL(g, l) __builtin_amdgcn_global_load_lds( \
    (const __attribute__((address_space(1))) void*)(g), \
    (__attribute__((address_space(3))) void*)(l), 16, 0, 0)

// Bijective XCD swizzle over the (x,y) grid; requires nwg_xy % 8 == 0.
#define XCD_SWZ(BMv, BNv)                                              \
  const int nwg_ = gridDim.x * gridDim.y;                              \
  const int flat_ = blockIdx.y * gridDim.x + blockIdx.x;               \
  const int swz_ = (flat_ & 7) * (nwg_ >> 3) + (flat_ >> 3);           \
  const int m0 = (swz_ / gridDim.x) * (BMv);                           \
  const int n0 = (swz_ % gridDim.x) * (BNv);

// =====================================================================
// Split-f16 MFMA GEMM (round-6 proven dual-32-stage version).
// MODE 0: 3-pass; MODE 2: 2-pass (B_lo dropped).
// C = acc + accL * 2^-11 (lo planes stored pre-scaled x2048).
// =====================================================================
template<int BM, int BN, int SPLITK, int MODE>
__global__ __launch_bounds__(256, 2) void gemm3p(const ushort* __restrict__ Ahi,
                                                 const ushort* __restrict__ Alo,
                                                 const ushort* __restrict__ Bhi,
                                                 const ushort* __restrict__ Blo,
                                                 float* __restrict__ C,
                                                 int M, int N, int K) {
  constexpr int WM = BM / 2, WN = BN / 2, TM = WM / 16, TN = WN / 16;
  constexpr int SA = BM / 16, SB = BN / 16;
  constexpr bool dropB = (MODE == 2);
  __shared__ __align__(16) ushort sAh[2][BM * 32], sAl[2][BM * 32];
  __shared__ __align__(16) ushort sBh[2][BN * 32];
  __shared__ __align__(16) ushort sBl[2][dropB ? 16 : BN * 32];
  const int tid = threadIdx.x, wid = tid >> 6, lane = tid & 63;
  XCD_SWZ(BM, BN)
  const int Kc = K / SPLITK, kbeg = blockIdx.z * Kc;
  const int wm0 = (wid >> 1) * WM, wn0 = (wid & 1) * WN;
  const int fr = lane & 15;
  const int lrow = lane >> 2;
  const int lkc = (lane & 3) ^ ((lane >> 3) & 3);
  const int fpo = fr * 32 + (((lane >> 4) ^ ((lane >> 1) & 3)) * 8);

  f32x4 acc[TM][TN], accL[TM][TN];
#pragma unroll
  for (int mi = 0; mi < TM; ++mi)
#pragma unroll
    for (int ni = 0; ni < TN; ++ni)
#pragma unroll
      for (int r = 0; r < 4; ++r) { acc[mi][ni][r] = 0.f; accL[mi][ni][r] = 0.f; }

  for (int k0 = 0; k0 < Kc; k0 += 64) {
    __syncthreads();
#pragma unroll
    for (int kk = 0; kk < 2; ++kk) {
      const int kg = kbeg + k0 + kk * 32 + lkc * 8;
#pragma unroll
      for (int i = 0; i < SA / 4; ++i) {
        const int seg = wid * (SA / 4) + i;
        const size_t ga = (size_t)(m0 + seg * 16 + lrow) * K + kg;
        GLL(&Ahi[ga], &sAh[kk][seg * 512]);
        GLL(&Alo[ga], &sAl[kk][seg * 512]);
      }
#pragma unroll
      for (int i = 0; i < SB / 4; ++i) {
        const int seg = wid * (SB / 4) + i;
        const size_t ga = (size_t)(n0 + seg * 16 + lrow) * K + kg;
        GLL(&Bhi[ga], &sBh[kk][seg * 512]);
        if constexpr (!dropB) GLL(&Blo[ga], &sBl[kk][seg * 512]);
      }
    }
    __syncthreads();

#pragma unroll
    for (int kk = 0; kk < 2; ++kk) {
      f16x8 ah[TM], al[TM], bh[TN], bl[TN];
#pragma unroll
      for (int mi = 0; mi < TM; ++mi) {
        const int r = (wm0 / 16 + mi) * 512 + fpo;
        ah[mi] = *(const f16x8*)&sAh[kk][r];
        al[mi] = *(const f16x8*)&sAl[kk][r];
      }
#pragma unroll
      for (int ni = 0; ni < TN; ++ni) {
        const int r = (wn0 / 16 + ni) * 512 + fpo;
        bh[ni] = *(const f16x8*)&sBh[kk][r];
        if constexpr (!dropB) bl[ni] = *(const f16x8*)&sBl[kk][r];
      }
#pragma unroll
      for (int mi = 0; mi < TM; ++mi)
#pragma unroll
        for (int ni = 0; ni < TN; ++ni) {
          acc[mi][ni] = __builtin_amdgcn_mfma_f32_16x16x32_f16(ah[mi], bh[ni], acc[mi][ni], 0, 0, 0);
          accL[mi][ni] = __builtin_amdgcn_mfma_f32_16x16x32_f16(al[mi], bh[ni], accL[mi][ni], 0, 0, 0);
          if constexpr (!dropB)
            accL[mi][ni] = __builtin_amdgcn_mfma_f32_16x16x32_f16(ah[mi], bl[ni], accL[mi][ni], 0, 0, 0);
        }
    }
  }

  float* __restrict__ Co = C + (size_t)blockIdx.z * M * N;
#pragma unroll
  for (int mi = 0; mi < TM; ++mi)
#pragma unroll
    for (int ni = 0; ni < TN; ++ni)
#pragma unroll
      for (int r = 0; r < 4; ++r)
        Co[(size_t)(m0 + wm0 + mi * 16 + (lane >> 4) * 4 + r) * N + n0 + wn0 + ni * 16 + fr] =
            acc[mi][ni][r] + accL[mi][ni][r] * (1.f / 2048.f);
}

// =====================================================================
// In-kernel dt projection tile: computes sp[br][l in t0..t0+32][d in
// d0..d0+256] = softplus(dtT @ dtw + bias) into LDS, via direct
// global->VGPR MFMA fragments (operands are ~1MB, L2-resident).
// Fragment map (derived from gemm3p's staging/read swizzle pair, which
// cancels: lane holds row = lane&15, k = (lane>>4)*8 .. +8).
// Deletes the dt_mfma kernel and the 100MB sp HBM round-trip.
// =====================================================================
__device__ __forceinline__ void dt_tile(const ushort* __restrict__ dtT_hi,
                                        const ushort* __restrict__ dtT_lo,
                                        const ushort* __restrict__ dw_hi,
                                        const ushort* __restrict__ dw_lo,
                                        const float* __restrict__ b1,
                                        const float* __restrict__ b2,
                                        int t0, int d0, int tid,
                                        float (*sp_s)[CH][260]) {
  const int wid = tid >> 6, lane = tid & 63;
  const int fr = lane & 15, kq = lane >> 4;
#pragma unroll
  for (int br = 0; br < 2; ++br) {
    const ushort* __restrict__ Ah = dtT_hi + br * 131072;
    const ushort* __restrict__ Al = dtT_lo + br * 131072;
    const ushort* __restrict__ Bh = dw_hi + br * 131072;
    const ushort* __restrict__ Bl = dw_lo + br * 131072;
    const float* __restrict__ bias = br ? b2 : b1;
    f32x4 acc[2][4], accL[2][4];
#pragma unroll
    for (int mi = 0; mi < 2; ++mi)
#pragma unroll
      for (int ni = 0; ni < 4; ++ni)
#pragma unroll
        for (int r = 0; r < 4; ++r) { acc[mi][ni][r] = 0.f; accL[mi][ni][r] = 0.f; }
#pragma unroll
    for (int kk = 0; kk < 2; ++kk) {
      f16x8 a_h[2], a_l[2], b_h[4], b_l[4];
#pragma unroll
      for (int mi = 0; mi < 2; ++mi) {
        const size_t off = (size_t)(t0 + mi * 16 + fr) * 64 + kk * 32 + kq * 8;
        a_h[mi] = *(const f16x8*)&Ah[off];
        a_l[mi] = *(const f16x8*)&Al[off];
      }
#pragma unroll
      for (int ni = 0; ni < 4; ++ni) {
        const size_t off = (size_t)(d0 + wid * 64 + ni * 16 + fr) * 64 + kk * 32 + kq * 8;
        b_h[ni] = *(const f16x8*)&Bh[off];
        b_l[ni] = *(const f16x8*)&Bl[off];
      }
#pragma unroll
      for (int mi = 0; mi < 2; ++mi)
#pragma unroll
        for (int ni = 0; ni < 4; ++ni) {
          acc[mi][ni] = __builtin_amdgcn_mfma_f32_16x16x32_f16(a_h[mi], b_h[ni], acc[mi][ni], 0, 0, 0);
          accL[mi][ni] = __builtin_amdgcn_mfma_f32_16x16x32_f16(a_l[mi], b_h[ni], accL[mi][ni], 0, 0, 0);
          accL[mi][ni] = __builtin_amdgcn_mfma_f32_16x16x32_f16(a_h[mi], b_l[ni], accL[mi][ni], 0, 0, 0);
        }
    }
#pragma unroll
    for (int ni = 0; ni < 4; ++ni) {
      const float bv = bias[d0 + wid * 64 + ni * 16 + fr];
#pragma unroll
      for (int mi = 0; mi < 2; ++mi)
#pragma unroll
        for (int r = 0; r < 4; ++r)
          sp_s[br][mi * 16 + kq * 4 + r][wid * 64 + ni * 16 + fr] =
              splus(acc[mi][ni][r] + accL[mi][ni][r] * (1.f / 2048.f) + bv);
    }
  }
}

__device__ __forceinline__ void split_store4h(float4 v, ushort* hi, ushort* lo, size_t i) {
  ushort h0 = f2h(v.x), h1 = f2h(v.y), h2 = f2h(v.z), h3 = f2h(v.w);
  *(ushort4*)&hi[i] = make_ushort4(h0, h1, h2, h3);
  *(ushort4*)&lo[i] = make_ushort4(f2h((v.x - h2f(h0)) * 2048.f), f2h((v.y - h2f(h1)) * 2048.f),
                                   f2h((v.z - h2f(h2)) * 2048.f), f2h((v.w - h2f(h3)) * 2048.f));
}

// One launch converting in_proj_w, hidden, x1w, x2w, dtw1, dtw2 -> f16 planes.
__global__ __launch_bounds__(256) void cvt_fused(const float* __restrict__ inw,
                                                 const float* __restrict__ hid,
                                                 const float* __restrict__ x1w,
                                                 const float* __restrict__ x2w,
                                                 const float* __restrict__ dtw1,
                                                 const float* __restrict__ dtw2,
                                                 ushort* __restrict__ w_hi, ushort* __restrict__ w_lo,
                                                 ushort* __restrict__ h_hi,
                                                 ushort* __restrict__ wx_hi, ushort* __restrict__ wx_lo,
                                                 ushort* __restrict__ dw_hi, ushort* __restrict__ dw_lo) {
  const int q = blockIdx.x * 256 + threadIdx.x;  // float4 index
  if (q >= 1048576 && q < 1572864) {
    const size_t i = (size_t)(q - 1048576) * 4;
    float4 v = *(const float4*)&hid[i];
    *(ushort4*)&h_hi[i] = make_ushort4(f2h(v.x), f2h(v.y), f2h(v.z), f2h(v.w));
    return;
  }
  const float* src; ushort* dhi; ushort* dlo; int base;
  if (q < 1048576)       { src = inw; dhi = w_hi;  dlo = w_lo;  base = q; }
  else if (q < 1622016)  { src = x1w; dhi = wx_hi; dlo = wx_lo; base = q - 1572864; }
  else if (q < 1671168)  { src = x2w; dhi = wx_hi + 196608; dlo = wx_lo + 196608; base = q - 1622016; }
  else if (q < 1703936)  { src = dtw1; dhi = dw_hi; dlo = dw_lo; base = q - 1671168; }
  else                   { src = dtw2; dhi = dw_hi + 131072; dlo = dw_lo + 131072; base = q - 1703936; }
  const size_t i = (size_t)base * 4;
  split_store4h(*(const float4*)&src[i], dhi, dlo, i);
}

__global__ __launch_bounds__(256) void reduce_out(const float* __restrict__ p,
                                                  float* __restrict__ o, int n) {
  const int i = (blockIdx.x * 256 + threadIdx.x) * 4;
  if (i >= n) return;
  float4 a = *(const float4*)&p[i];
  float4 b = *(const float4*)&p[(size_t)n + i];
  float4 c = *(const float4*)&p[(size_t)2 * n + i];
  float4 d = *(const float4*)&p[(size_t)3 * n + i];
  *(float4*)&o[i] = make_float4(a.x + b.x + c.x + d.x, a.y + b.y + c.y + d.y,
                                a.z + b.z + c.z + d.z, a.w + b.w + c.w + d.w);
}

// =====================================================================
// Conv (w=4, causal) + bias + SiLU -> transposed f16 hi/lo planes (l,d).
// Also: silu(z) transposed to (l,d) interleaved ushort2 plane.
// =====================================================================
__global__ __launch_bounds__(256) void conv_tr_kernel(const float* __restrict__ xz,
                                                      const float* __restrict__ cw,
                                                      const float* __restrict__ cb,
                                                      ushort* __restrict__ xcT_hi,
                                                      ushort* __restrict__ xcT_lo,
                                                      ushort2* __restrict__ zs) {
  const int l0 = blockIdx.x * 64, d0 = blockIdx.y * 64;
  const int tid = threadIdx.x;
  __shared__ float xin[64][68];  // cols 0..66 = l0-3 .. l0+63
  __shared__ float To[64][65];
  __shared__ float cwS[64][4];
  __shared__ float cbS[64];

  for (int i = tid; i < 1024; i += 256) {
    const int d = i >> 4, q = i & 15;
    float4 v = *(const float4*)&xz[(size_t)(d0 + d) * SEQ + l0 + q * 4];
    xin[d][3 + q * 4 + 0] = v.x; xin[d][3 + q * 4 + 1] = v.y;
    xin[d][3 + q * 4 + 2] = v.z; xin[d][3 + q * 4 + 3] = v.w;
  }
  if (tid < 192) {
    const int j = tid >> 6, d = tid & 63;
    const int l = l0 - 3 + j;
    xin[d][j] = (l >= 0) ? xz[(size_t)(d0 + d) * SEQ + l] : 0.f;
  }
  if (tid < 64) {
    cbS[tid] = cb[d0 + tid];
    float4 w = *(const float4*)&cw[(d0 + tid) * 4];
    cwS[tid][0] = w.x; cwS[tid][1] = w.y; cwS[tid][2] = w.z; cwS[tid][3] = w.w;
  }
  __syncthreads();

  for (int i = tid; i < 4096; i += 256) {
    const int d = i >> 6, l = i & 63;
    float a = cbS[d] + cwS[d][0] * xin[d][l] + cwS[d][1] * xin[d][l + 1] +
              cwS[d][2] * xin[d][l + 2] + cwS[d][3] * xin[d][l + 3];
    To[d][l] = a / (1.f + __expf(-a));
  }
  __syncthreads();

  for (int i = tid; i < 4096; i += 256) {
    const int l = i >> 6, dd = i & 63;
    float v = To[dd][l];  // stride-65: conflict-free
    ushort h = f2h(v);
    xcT_hi[(size_t)(l0 + l) * DIN + d0 + dd] = h;
    xcT_lo[(size_t)(l0 + l) * DIN + d0 + dd] = f2h((v - h2f(h)) * 2048.f);
  }
  __syncthreads();  // To fully consumed; reuse for z tile

  for (int i = tid; i < 1024; i += 256) {
    const int d = i >> 4, q = i & 15;
    float4 v = *(const float4*)&xz[(size_t)(DIN + d0 + d) * SEQ + l0 + q * 4];
    To[d][q * 4 + 0] = v.x / (1.f + __expf(-v.x));
    To[d][q * 4 + 1] = v.y / (1.f + __expf(-v.y));
    To[d][q * 4 + 2] = v.z / (1.f + __expf(-v.z));
    To[d][q * 4 + 3] = v.w / (1.f + __expf(-v.w));
  }
  __syncthreads();
  for (int i = tid; i < 4096; i += 256) {
    const int l = i >> 6, dd = i & 63;
    zs[(size_t)(l0 + l) * DIN + d0 + dd] = split2(To[dd][l]);
  }
}

// Reduce 16 x_proj split-K slabs (SEQ x 192, l-major) -> B/C tables +
// dt rows as (l,r) f16 hi/lo planes.
__global__ __launch_bounds__(256) void reduce_dblT_kernel(const float* __restrict__ p,
                                                          float* __restrict__ BT1,
                                                          float* __restrict__ CT1,
                                                          float* __restrict__ BT2,
                                                          float* __restrict__ CT2,
                                                          ushort* __restrict__ dtT_hi,
                                                          ushort* __restrict__ dtT_lo) {
  const int NE = SEQ * 192;
  const int idx = blockIdx.x * 256 + threadIdx.x;
  float s = 0.f;
#pragma unroll
  for (int cc = 0; cc < 16; ++cc) s += p[(size_t)cc * NE + idx];
  const int l = idx / 192, k = idx - l * 192;
  if (k < 64) {
    const size_t off = (size_t)l * 64 + k;
    const ushort hh = f2h(s);
    dtT_hi[off] = hh; dtT_lo[off] = f2h((s - h2f(hh)) * 2048.f);
  } else if (k < 80)  BT1[l * NST + (k - 64)] = s;
  else if (k < 96)    CT1[l * NST + (k - 80)] = s;
  else if (k < 160) {
    const size_t off = 131072 + (size_t)l * 64 + (k - 96);
    const ushort hh = f2h(s);
    dtT_hi[off] = hh; dtT_lo[off] = f2h((s - h2f(hh)) * 2048.f);
  }
  else if (k < 176)   BT2[l * NST + (k - 160)] = s;
  else                CT2[l * NST + (k - 176)] = s;
}

// =====================================================================
// Chunked selective scan, BOTH branches fused per thread.
// sp computed IN-KERNEL (dt_tile MFMA -> LDS); u as f16 hi/lo planes.
// =====================================================================
__global__ __launch_bounds__(256) void scan_phase_a(const ushort* __restrict__ uhi,
                                                    const ushort* __restrict__ ulo,
                                                    const ushort* __restrict__ dtT_hi,
                                                    const ushort* __restrict__ dtT_lo,
                                                    const ushort* __restrict__ dw_hi,
                                                    const ushort* __restrict__ dw_lo,
                                                    const float* __restrict__ dtb1,
                                                    const float* __restrict__ dtb2,
                                                    const float* __restrict__ BT1,
                                                    const float* __restrict__ BT2,
                                                    const float* __restrict__ Al1,
                                                    const float* __restrict__ Al2,
                                                    float* __restrict__ hend,
                                                    float* __restrict__ Pend) {
  const int c = blockIdx.y, t0 = c * CH;
  const int d0b = blockIdx.x * 256;
  const int d = d0b + threadIdx.x;
  const size_t gbase = (size_t)t0 * DIN + d;

  __shared__ __align__(16) float Bs[2][CH][NST];
  __shared__ __align__(16) float sp_s[2][CH][260];
  {
    const int j = threadIdx.x;  // 2*CH*NST floats = 256 float4
    if (j < 128) ((float4*)&Bs[0][0][0])[j] = ((const float4*)&BT1[(size_t)t0 * NST])[j];
    else ((float4*)&Bs[1][0][0])[j - 128] = ((const float4*)&BT2[(size_t)t0 * NST])[j - 128];
  }
  dt_tile(dtT_hi, dtT_lo, dw_hi, dw_lo, dtb1, dtb2, t0, d0b, threadIdx.x, sp_s);
  __syncthreads();

  bool fast = true;
#pragma unroll
  for (int n = 0; n < NST; ++n) {
    float k1 = __expf(Al1[(size_t)d * NST + n]);
    float k2 = __expf(Al2[(size_t)d * NST + n]);
    fast = fast && (fabsf(k1 - (float)(n + 1)) < 1e-3f) && (fabsf(k2 - (float)(n + 1)) < 1e-3f);
  }
  float h1[NST], h2[NST];
#pragma unroll
  for (int n = 0; n < NST; ++n) { h1[n] = 0.f; h2[n] = 0.f; }
  float S1 = 0.f, S2 = 0.f;

  if (fast) {
    for (int tt = 0; tt < CH / 4; ++tt) {
      float s1[4], s2[4], ua[4];
#pragma unroll
      for (int j = 0; j < 4; ++j) {
        const size_t idx = gbase + (size_t)(tt * 4 + j) * DIN;
        s1[j] = sp_s[0][tt * 4 + j][threadIdx.x];
        s2[j] = sp_s[1][tt * 4 + j][threadIdx.x];
        ua[j] = h2f(uhi[idx]) + h2f(ulo[idx]) * (1.f / 2048.f);
      }
#pragma unroll
      for (int j = 0; j < 4; ++j) {
        const int t = tt * 4 + j;
        S1 += s1[j]; S2 += s2[j];
        const float spu1 = s1[j] * ua[j], spu2 = s2[j] * ua[j];
        float p[NST];
        powers16(__expf(-s1[j]), p);
#pragma unroll
        for (int n = 0; n < NST; ++n) h1[n] = fmaf(p[n], h1[n], spu1 * Bs[0][t][n]);
        powers16(__expf(-s2[j]), p);
#pragma unroll
        for (int n = 0; n < NST; ++n) h2[n] = fmaf(p[n], h2[n], spu2 * Bs[1][t][n]);
      }
    }
  } else {
    float A1e[NST], A2e[NST];
#pragma unroll
    for (int n = 0; n < NST; ++n) {
      A1e[n] = -__expf(Al1[(size_t)d * NST + n]) * LOG2E;
      A2e[n] = -__expf(Al2[(size_t)d * NST + n]) * LOG2E;
    }
    for (int tt = 0; tt < CH / 4; ++tt) {
      float s1[4], s2[4], ua[4];
#pragma unroll
      for (int j = 0; j < 4; ++j) {
        const size_t idx = gbase + (size_t)(tt * 4 + j) * DIN;
        s1[j] = sp_s[0][tt * 4 + j][threadIdx.x];
        s2[j] = sp_s[1][tt * 4 + j][threadIdx.x];
        ua[j] = h2f(uhi[idx]) + h2f(ulo[idx]) * (1.f / 2048.f);
      }
#pragma unroll
      for (int j = 0; j < 4; ++j) {
        const int t = tt * 4 + j;
        S1 += s1[j]; S2 += s2[j];
        const float spu1 = s1[j] * ua[j], spu2 = s2[j] * ua[j];
#pragma unroll
        for (int n = 0; n < NST; ++n) {
          h1[n] = fmaf(exp2f(A1e[n] * s1[j]), h1[n], spu1 * Bs[0][t][n]);
          h2[n] = fmaf(exp2f(A2e[n] * s2[j]), h2[n], spu2 * Bs[1][t][n]);
        }
      }
    }
  }

  float P1[NST], P2[NST];
  if (fast) {
    powers16(__expf(-S1), P1);
    powers16(__expf(-S2), P2);
  } else {
#pragma unroll
    for (int n = 0; n < NST; ++n) {
      P1[n] = exp2f(-__expf(Al1[(size_t)d * NST + n]) * LOG2E * S1);
      P2[n] = exp2f(-__expf(Al2[(size_t)d * NST + n]) * LOG2E * S2);
    }
  }
  const size_t b1 = ((size_t)c * DIN + d) * NST;
  const size_t b2 = ((size_t)(NCH + c) * DIN + d) * NST;
#pragma unroll
  for (int n = 0; n < NST; n += 4) {
    *(float4*)&hend[b1 + n] = make_float4(h1[n], h1[n + 1], h1[n + 2], h1[n + 3]);
    *(float4*)&Pend[b1 + n] = make_float4(P1[n], P1[n + 1], P1[n + 2], P1[n + 3]);
    *(float4*)&hend[b2 + n] = make_float4(h2[n], h2[n + 1], h2[n + 2], h2[n + 3]);
    *(float4*)&Pend[b2 + n] = make_float4(P2[n], P2[n + 1], P2[n + 2], P2[n + 3]);
  }
}

// Merged: blocks [0,256) do the chunk-carry (hin overwrites Pend in place);
// blocks [256,2304) convert outw -> f16 hi plane.
__global__ __launch_bounds__(256) void carry_cvt(const float* __restrict__ hend,
                                                 float* __restrict__ PendHin,
                                                 const float* __restrict__ outw,
                                                 ushort* __restrict__ ow_hi) {
  const int b = blockIdx.x;
  if (b < 256) {
    const int flat = b * 256 + threadIdx.x;
    const int br = flat >> 15;
    const int dn = flat & 32767;
    float h = 0.f;
    for (int c = 0; c < NCH; ++c) {
      size_t idx = ((size_t)(br * NCH + c) << 15) + dn;
      float Pv = PendHin[idx];
      float he = hend[idx];
      PendHin[idx] = h;
      h = fmaf(Pv, h, he);
    }
  } else {
    const size_t i = ((size_t)(b - 256) * 256 + threadIdx.x) * 4;  // < 2,097,152
    float4 v = *(const float4*)&outw[i];
    *(ushort4*)&ow_hi[i] = make_ushort4(f2h(v.x), f2h(v.y), f2h(v.z), f2h(v.w));
  }
}

// Phase C fused: both branches per thread; emits yd = (y1-y2+(D1-D2)u)*silu(z)
// directly as f16 hi/lo planes IN PLACE over the u planes.
__global__ __launch_bounds__(256) void scan_phase_c(const ushort* __restrict__ uhi,
                                                    const ushort* __restrict__ ulo,
                                                    const ushort* __restrict__ dtT_hi,
                                                    const ushort* __restrict__ dtT_lo,
                                                    const ushort* __restrict__ dw_hi,
                                                    const ushort* __restrict__ dw_lo,
                                                    const float* __restrict__ dtb1,
                                                    const float* __restrict__ dtb2,
                                                    const float* __restrict__ BT1,
                                                    const float* __restrict__ CT1,
                                                    const float* __restrict__ BT2,
                                                    const float* __restrict__ CT2,
                                                    const float* __restrict__ Al1,
                                                    const float* __restrict__ Al2,
                                                    const float* __restrict__ D1,
                                                    const float* __restrict__ D2,
                                                    const float* __restrict__ hin,
                                                    const ushort2* __restrict__ zs,
                                                    ushort* __restrict__ yd_hi,
                                                    ushort* __restrict__ yd_lo) {
  const int c = blockIdx.y, t0 = c * CH;
  const int d0b = blockIdx.x * 256;
  const int d = d0b + threadIdx.x;
  const size_t gbase = (size_t)t0 * DIN + d;

  __shared__ __align__(16) float Bs[2][CH][NST];
  __shared__ __align__(16) float Cs[2][CH][NST];
  __shared__ __align__(16) float sp_s[2][CH][260];
  {
    const int j = threadIdx.x;
    if (j < 128) {
      ((float4*)&Bs[0][0][0])[j] = ((const float4*)&BT1[(size_t)t0 * NST])[j];
      ((float4*)&Cs[0][0][0])[j] = ((const float4*)&CT1[(size_t)t0 * NST])[j];
    } else {
      ((float4*)&Bs[1][0][0])[j - 128] = ((const float4*)&BT2[(size_t)t0 * NST])[j - 128];
      ((float4*)&Cs[1][0][0])[j - 128] = ((const float4*)&CT2[(size_t)t0 * NST])[j - 128];
    }
  }
  dt_tile(dtT_hi, dtT_lo, dw_hi, dw_lo, dtb1, dtb2, t0, d0b, threadIdx.x, sp_s);
  __syncthreads();

  bool fast = true;
#pragma unroll
  for (int n = 0; n < NST; ++n) {
    float k1 = __expf(Al1[(size_t)d * NST + n]);
    float k2 = __expf(Al2[(size_t)d * NST + n]);
    fast = fast && (fabsf(k1 - (float)(n + 1)) < 1e-3f) && (fabsf(k2 - (float)(n + 1)) < 1e-3f);
  }
  const float Ddd = D1[d] - D2[d];
  float h1[NST], h2[NST];
  const size_t hb1 = ((size_t)c * DIN + d) * NST;
  const size_t hb2 = ((size_t)(NCH + c) * DIN + d) * NST;
#pragma unroll
  for (int n = 0; n < NST; n += 4) {
    float4 v1 = *(const float4*)&hin[hb1 + n];
    h1[n] = v1.x; h1[n + 1] = v1.y; h1[n + 2] = v1.z; h1[n + 3] = v1.w;
    float4 v2 = *(const float4*)&hin[hb2 + n];
    h2[n] = v2.x; h2[n + 1] = v2.y; h2[n + 2] = v2.z; h2[n + 3] = v2.w;
  }

  if (fast) {
    for (int tt = 0; tt < CH / 4; ++tt) {
      float s1[4], s2[4], ua[4];
#pragma unroll
      for (int j = 0; j < 4; ++j) {
        const size_t idx = gbase + (size_t)(tt * 4 + j) * DIN;
        s1[j] = sp_s[0][tt * 4 + j][threadIdx.x];
        s2[j] = sp_s[1][tt * 4 + j][threadIdx.x];
        ua[j] = h2f(uhi[idx]) + h2f(ulo[idx]) * (1.f / 2048.f);
      }
#pragma unroll
      for (int j = 0; j < 4; ++j) {
        const int t = tt * 4 + j;
        const size_t idx = gbase + (size_t)t * DIN;
        const float spu1 = s1[j] * ua[j], spu2 = s2[j] * ua[j];
        float p[NST];
        float y1 = 0.f, y2 = 0.f;
        powers16(__expf(-s1[j]), p);
#pragma unroll
        for (int n = 0; n < NST; ++n) {
          h1[n] = fmaf(p[n], h1[n], spu1 * Bs[0][t][n]);
          y1 = fmaf(h1[n], Cs[0][t][n], y1);
        }
        powers16(__expf(-s2[j]), p);
#pragma unroll
        for (int n = 0; n < NST; ++n) {
          h2[n] = fmaf(p[n], h2[n], spu2 * Bs[1][t][n]);
          y2 = fmaf(h2[n], Cs[1][t][n], y2);
        }
        const float zv = join2(zs[idx]);
        const float yd = (y1 - y2 + Ddd * ua[j]) * zv;
        const ushort hh = f2h(yd);
        yd_hi[idx] = hh;
        yd_lo[idx] = f2h((yd - h2f(hh)) * 2048.f);
      }
    }
  } else {
    float A1e[NST], A2e[NST];
#pragma unroll
    for (int n = 0; n < NST; ++n) {
      A1e[n] = -__expf(Al1[(size_t)d * NST + n]) * LOG2E;
      A2e[n] = -__expf(Al2[(size_t)d * NST + n]) * LOG2E;
    }
    for (int tt = 0; tt < CH / 4; ++tt) {
      float s1[4], s2[4], ua[4];
#pragma unroll
      for (int j = 0; j < 4; ++j) {
        const size_t idx = gbase + (size_t)(tt * 4 + j) * DIN;
        s1[j] = sp_s[0][tt * 4 + j][threadIdx.x];
        s2[j] = sp_s[1][tt * 4 + j][threadIdx.x];
        ua[j] = h2f(uhi[idx]) + h2f(ulo[idx]) * (1.f / 2048.f);
      }
#pragma unroll
      for (int j = 0; j < 4; ++j) {
        const int t = tt * 4 + j;
        const size_t idx = gbase + (size_t)t * DIN;
        const float spu1 = s1[j] * ua[j], spu2 = s2[j] * ua[j];
        float y1 = 0.f, y2 = 0.f;
#pragma unroll
        for (int n = 0; n < NST; ++n) {
          h1[n] = fmaf(exp2f(A1e[n] * s1[j]), h1[n], spu1 * Bs[0][t][n]);
          y1 = fmaf(h1[n], Cs[0][t][n], y1);
          h2[n] = fmaf(exp2f(A2e[n] * s2[j]), h2[n], spu2 * Bs[1][t][n]);
          y2 = fmaf(h2[n], Cs[1][t][n], y2);
        }
        const float zv = join2(zs[idx]);
        const float yd = (y1 - y2 + Ddd * ua[j]) * zv;
        const ushort hh = f2h(yd);
        yd_hi[idx] = hh;
        yd_lo[idx] = f2h((yd - h2f(hh)) * 2048.f);
      }
    }
  }
}

// =====================================================================
extern "C" void kernel_launch(void* const* d_in, const int* in_sizes, int n_in,
                              void* d_out, int out_size, void* d_ws, size_t ws_size,
                              hipStream_t stream) {
  const float* hidden = (const float*)d_in[0];
  const float* in_proj_w = (const float*)d_in[1];
  const float* conv_w = (const float*)d_in[2];
  const float* conv_b = (const float*)d_in[3];
  const float* x1w = (const float*)d_in[4];
  const float* dtw1 = (const float*)d_in[5];
  const float* dtb1 = (const float*)d_in[6];
  const float* Al1 = (const float*)d_in[7];
  const float* D1 = (const float*)d_in[8];
  const float* x2w = (const float*)d_in[9];
  const float* dtw2 = (const float*)d_in[10];
  const float* dtb2 = (const float*)d_in[11];
  const float* Al2 = (const float*)d_in[12];
  const float* D2 = (const float*)d_in[13];
  const float* outw = (const float*)d_in[14];
  float* out = (float*)d_out;

  // Workspace layout (floats), same 34.47M footprint.
  float* ws = (float*)d_ws;
  float* xz = ws;                                    // 8.39M  (x rows, z rows)
  float* xcTbuf = xz + (size_t)4096 * SEQ;           // 4.19M  u f16 hi/lo planes
  float* dtTbuf = xcTbuf + (size_t)SEQ * DIN;        // 393K   dtT f16 hi/lo planes
  float* spbuf1 = dtTbuf + (size_t)192 * SEQ;        // 4.19M  (xp/opart partials)
  float* spbuf2 = spbuf1 + (size_t)SEQ * DIN;        // 4.19M  (partials + dw tail)
  float* zsbuf = spbuf2 + (size_t)SEQ * DIN;         // 4.19M  silu(z) ushort2 plane
  float* hendB = zsbuf + (size_t)SEQ * DIN;          // 4.19M
  float* PendB = hendB + (size_t)2 * NCH * DIN * NST;// 4.19M
  float* BT1 = PendB + (size_t)2 * NCH * DIN * NST;  // 32K each
  float* CT1 = BT1 + (size_t)SEQ * NST;
  float* BT2 = CT1 + (size_t)SEQ * NST;
  float* CT2 = BT2 + (size_t)SEQ * NST;
  float* wxp = CT2 + (size_t)SEQ * NST;              // 393K stacked x_proj W planes

  // Aliases (lifetime-disjoint):
  ushort* xcT_hi = (ushort*)xcTbuf;                  // u planes, steps 3..scan C
  ushort* xcT_lo = (ushort*)(xcTbuf + 2097152);
  ushort* dtT_hi = (ushort*)dtTbuf;                  // dt rows (l,64) x 2 branches
  ushort* dtT_lo = dtT_hi + 262144;
  ushort2* zs = (ushort2*)zsbuf;                     // interleaved silu(z) plane
  ushort* w_hi = (ushort*)zsbuf;                     // in_proj_w planes (dead after step 2,
  ushort* w_lo = (ushort*)(zsbuf + 2097152);         //   before conv writes zs plane)
  ushort* h_hi = (ushort*)hendB;                     // hidden hi plane (dead after step 2)
  // dtw planes: tail of spbuf2 (last 262144 floats = 1MB).  Lifetime:
  // written step 1; read by scan_a/scan_c (step 7).  xp_part (steps 4-5)
  // ends at spbuf2+2.1M floats < spbuf2+3.93M -> no clash.  opart (step 8)
  // overlaps but dw is dead by then.
  ushort* dw_hi = (ushort*)(spbuf2 + 3932160);
  ushort* dw_lo = dw_hi + 262144;
  ushort* wx_hi = (ushort*)wxp;                      // stacked x_proj weights 192x2048
  ushort* wx_lo = (ushort*)(wxp + 196608);
  float* xp_part = spbuf1;                           // 16 slabs x SEQ*192*4B = 25.2MB
  ushort* yd_hi = (ushort*)xcTbuf;                   // yd planes overwrite u in-place
  ushort* yd_lo = (ushort*)(xcTbuf + 2097152);
  ushort* ow_hi = (ushort*)xz;                       // outw hi plane in dead xz
  float* opart = spbuf1;                             // out_proj partials: 33.6MB

  dim3 blk(256);

  // 1) fused split-convert: in_proj_w, hidden (hi only), x1w, x2w, dtw1, dtw2
  cvt_fused<<<dim3(6784), blk, 0, stream>>>(in_proj_w, hidden, x1w, x2w, dtw1, dtw2,
                                            w_hi, w_lo, h_hi, wx_hi, wx_lo, dw_hi, dw_lo);

  // 2) in_proj via f16 MFMA 2-pass (dual-32 stages) -> xz (e,l)
  gemm3p<128, 128, 1, 2><<<dim3(SEQ / 128, 4096 / 128, 1), blk, 0, stream>>>(
      w_hi, w_lo, h_hi, h_hi, xz, 4096, SEQ, DMODEL);

  // 3) conv + silu -> u f16 planes (l,d); silu(z) -> ushort2 plane (l,d)
  conv_tr_kernel<<<dim3(SEQ / 64, DIN / 64), blk, 0, stream>>>(
      xz, conv_w, conv_b, xcT_hi, xcT_lo, zs);

  // 4) x_proj swapped: C[l, k(192)] = sum_d xcT[l,d]*wx[k,d], split-K=16
  gemm3p<128, 64, 16, 0><<<dim3(192 / 64, SEQ / 128, 16), blk, 0, stream>>>(
      xcT_hi, xcT_lo, wx_hi, wx_lo, xp_part, SEQ, 192, DIN);

  // 5) reduce 16 slabs -> B/C tables + dtT f16 planes
  reduce_dblT_kernel<<<dim3(192 * SEQ / 256), blk, 0, stream>>>(
      xp_part, BT1, CT1, BT2, CT2, dtT_hi, dtT_lo);

  // 6+7) chunked scan with IN-KERNEL dt projection (dt_mfma deleted)
  scan_phase_a<<<dim3(DIN / 256, NCH), blk, 0, stream>>>(
      xcT_hi, xcT_lo, dtT_hi, dtT_lo, dw_hi, dw_lo, dtb1, dtb2,
      BT1, BT2, Al1, Al2, hendB, PendB);
  carry_cvt<<<dim3(2304), blk, 0, stream>>>(hendB, PendB, outw, ow_hi);
  scan_phase_c<<<dim3(DIN / 256, NCH), blk, 0, stream>>>(
      xcT_hi, xcT_lo, dtT_hi, dtT_lo, dw_hi, dw_lo, dtb1, dtb2,
      BT1, CT1, BT2, CT2, Al1, Al2, D1, D2, PendB, zs, yd_hi, yd_lo);

  // 8) out_proj via f16 MFMA 2-pass (dual-32 stages), split-K=4
  gemm3p<128, 128, 4, 2><<<dim3(DMODEL / 128, SEQ / 128, 4), blk, 0, stream>>>(
      yd_hi, yd_lo, ow_hi, ow_hi, opart, SEQ, DMODEL, DIN);
  reduce_out<<<dim3(SEQ * DMODEL / 1024), blk, 0, stream>>>(opart, out, SEQ * DMODEL);
}

// Round 10
// 330.126 us; speedup vs baseline: 1.1985x; 1.1985x over previous
//
#include <hip/hip_runtime.h>
#include <math.h>

#define SEQ 2048
#define DMODEL 1024
#define DIN 2048
#define NST 16
#define DTR 64
#define CH 32
#define NCH (SEQ / CH)
#define LOG2E 1.4426950408889634f

typedef __attribute__((ext_vector_type(8))) _Float16 f16x8;
typedef __attribute__((ext_vector_type(4))) float f32x4;

// f16 split (11-bit mantissa): hi = f16(v), lo = f16((v-hi)*2048).
// hi + lo*2^-11 reconstructs to ~2^-22 relative: NOT a precision cut.
// Scalar-consumed tensors (sp, silu(z)) store hi/lo INTERLEAVED as ushort2
// (one coalesced 4B store per element; round-4 lesson: split-plane 2B
// stores in MFMA fragment layout = 4.6x write amp).
__device__ __forceinline__ ushort f2h(float f) {
  union { _Float16 h; ushort u; } c; c.h = (_Float16)f; return c.u;
}
__device__ __forceinline__ float h2f(ushort u) {
  union { ushort u; _Float16 h; } c; c.u = u; return (float)c.h;
}
__device__ __forceinline__ ushort2 split2(float v) {
  ushort hh = f2h(v);
  return make_ushort2(hh, f2h((v - h2f(hh)) * 2048.f));
}
__device__ __forceinline__ float join2(ushort2 p) {
  return h2f(p.x) + h2f(p.y) * (1.f / 2048.f);
}
__device__ __forceinline__ float splus(float v) {
  return v > 20.f ? v : log1pf(__expf(v));
}
// p[n] = e^(n+1), depth-4 mul tree (no transcendentals).
__device__ __forceinline__ void powers16(float e, float* p) {
  float e2 = e * e, e4 = e2 * e2, e8 = e4 * e4;
  p[0] = e;       p[1] = e2;       p[2] = e2 * e;   p[3] = e4;
  p[4] = e4 * e;  p[5] = e4 * e2;  p[6] = e4 * p[2]; p[7] = e8;
  p[8] = e8 * e;  p[9] = e8 * e2;  p[10] = e8 * p[2]; p[11] = e8 * e4;
  p[12] = e8 * p[4]; p[13] = e8 * p[5]; p[14] = e8 * p[6]; p[15] = e8 * e8;
}

#define GLL(g, l) __builtin_amdgcn_global_load_lds( \
    (const __attribute__((address_space(1))) void*)(g), \
    (__attribute__((address_space(3))) void*)(l), 16, 0, 0)

// Bijective XCD swizzle over the (x,y) grid; requires nwg_xy % 8 == 0.
#define XCD_SWZ(BMv, BNv)                                              \
  const int nwg_ = gridDim.x * gridDim.y;                              \
  const int flat_ = blockIdx.y * gridDim.x + blockIdx.x;               \
  const int swz_ = (flat_ & 7) * (nwg_ >> 3) + (flat_ >> 3);           \
  const int m0 = (swz_ / gridDim.x) * (BMv);                           \
  const int n0 = (swz_ % gridDim.x) * (BNv);

// =====================================================================
// Split-f16 MFMA GEMM (round-6 proven dual-32-stage version).
// MODE 0: 3-pass; MODE 2: 2-pass (B_lo dropped).
// C = acc + accL * 2^-11 (lo planes stored pre-scaled x2048).
// =====================================================================
template<int BM, int BN, int SPLITK, int MODE>
__global__ __launch_bounds__(256, 2) void gemm3p(const ushort* __restrict__ Ahi,
                                                 const ushort* __restrict__ Alo,
                                                 const ushort* __restrict__ Bhi,
                                                 const ushort* __restrict__ Blo,
                                                 float* __restrict__ C,
                                                 int M, int N, int K) {
  constexpr int WM = BM / 2, WN = BN / 2, TM = WM / 16, TN = WN / 16;
  constexpr int SA = BM / 16, SB = BN / 16;
  constexpr bool dropB = (MODE == 2);
  __shared__ __align__(16) ushort sAh[2][BM * 32], sAl[2][BM * 32];
  __shared__ __align__(16) ushort sBh[2][BN * 32];
  __shared__ __align__(16) ushort sBl[2][dropB ? 16 : BN * 32];
  const int tid = threadIdx.x, wid = tid >> 6, lane = tid & 63;
  XCD_SWZ(BM, BN)
  const int Kc = K / SPLITK, kbeg = blockIdx.z * Kc;
  const int wm0 = (wid >> 1) * WM, wn0 = (wid & 1) * WN;
  const int fr = lane & 15;
  const int lrow = lane >> 2;
  const int lkc = (lane & 3) ^ ((lane >> 3) & 3);
  const int fpo = fr * 32 + (((lane >> 4) ^ ((lane >> 1) & 3)) * 8);

  f32x4 acc[TM][TN], accL[TM][TN];
#pragma unroll
  for (int mi = 0; mi < TM; ++mi)
#pragma unroll
    for (int ni = 0; ni < TN; ++ni)
#pragma unroll
      for (int r = 0; r < 4; ++r) { acc[mi][ni][r] = 0.f; accL[mi][ni][r] = 0.f; }

  for (int k0 = 0; k0 < Kc; k0 += 64) {
    __syncthreads();
#pragma unroll
    for (int kk = 0; kk < 2; ++kk) {
      const int kg = kbeg + k0 + kk * 32 + lkc * 8;
#pragma unroll
      for (int i = 0; i < SA / 4; ++i) {
        const int seg = wid * (SA / 4) + i;
        const size_t ga = (size_t)(m0 + seg * 16 + lrow) * K + kg;
        GLL(&Ahi[ga], &sAh[kk][seg * 512]);
        GLL(&Alo[ga], &sAl[kk][seg * 512]);
      }
#pragma unroll
      for (int i = 0; i < SB / 4; ++i) {
        const int seg = wid * (SB / 4) + i;
        const size_t ga = (size_t)(n0 + seg * 16 + lrow) * K + kg;
        GLL(&Bhi[ga], &sBh[kk][seg * 512]);
        if constexpr (!dropB) GLL(&Blo[ga], &sBl[kk][seg * 512]);
      }
    }
    __syncthreads();

#pragma unroll
    for (int kk = 0; kk < 2; ++kk) {
      f16x8 ah[TM], al[TM], bh[TN], bl[TN];
#pragma unroll
      for (int mi = 0; mi < TM; ++mi) {
        const int r = (wm0 / 16 + mi) * 512 + fpo;
        ah[mi] = *(const f16x8*)&sAh[kk][r];
        al[mi] = *(const f16x8*)&sAl[kk][r];
      }
#pragma unroll
      for (int ni = 0; ni < TN; ++ni) {
        const int r = (wn0 / 16 + ni) * 512 + fpo;
        bh[ni] = *(const f16x8*)&sBh[kk][r];
        if constexpr (!dropB) bl[ni] = *(const f16x8*)&sBl[kk][r];
      }
#pragma unroll
      for (int mi = 0; mi < TM; ++mi)
#pragma unroll
        for (int ni = 0; ni < TN; ++ni) {
          acc[mi][ni] = __builtin_amdgcn_mfma_f32_16x16x32_f16(ah[mi], bh[ni], acc[mi][ni], 0, 0, 0);
          accL[mi][ni] = __builtin_amdgcn_mfma_f32_16x16x32_f16(al[mi], bh[ni], accL[mi][ni], 0, 0, 0);
          if constexpr (!dropB)
            accL[mi][ni] = __builtin_amdgcn_mfma_f32_16x16x32_f16(ah[mi], bl[ni], accL[mi][ni], 0, 0, 0);
        }
    }
  }

  float* __restrict__ Co = C + (size_t)blockIdx.z * M * N;
#pragma unroll
  for (int mi = 0; mi < TM; ++mi)
#pragma unroll
    for (int ni = 0; ni < TN; ++ni)
#pragma unroll
      for (int r = 0; r < 4; ++r)
        Co[(size_t)(m0 + wm0 + mi * 16 + (lane >> 4) * 4 + r) * N + n0 + wn0 + ni * 16 + fr] =
            acc[mi][ni][r] + accL[mi][ni][r] * (1.f / 2048.f);
}

// =====================================================================
// dt projection on MFMA: C[l,d] = sum_r dtT[l,r]*dtw[d,r], K=64 = one
// dual-32 stage (single barrier pair).  Fused bias+softplus epilogue;
// sp output as interleaved ushort2 (l,d).  (r9 lesson: fusing this into
// the scans costs 176 VGPR -> occupancy collapse; keep it separate.)
// =====================================================================
__global__ __launch_bounds__(256, 2) void dt_mfma(const ushort* __restrict__ dtT_hi,
                                                  const ushort* __restrict__ dtT_lo,
                                                  const ushort* __restrict__ dw_hi,
                                                  const ushort* __restrict__ dw_lo,
                                                  const float* __restrict__ b1,
                                                  const float* __restrict__ b2,
                                                  ushort2* __restrict__ sp1,
                                                  ushort2* __restrict__ sp2) {
  const int br = blockIdx.z;
  const ushort* __restrict__ Ah = dtT_hi + (size_t)br * 131072;
  const ushort* __restrict__ Al_ = dtT_lo + (size_t)br * 131072;
  const ushort* __restrict__ Bh = dw_hi + (size_t)br * 131072;
  const ushort* __restrict__ Bl = dw_lo + (size_t)br * 131072;
  const float* __restrict__ bias = br ? b2 : b1;
  ushort2* __restrict__ o = br ? sp2 : sp1;
  __shared__ __align__(16) ushort sAh[2][4096], sAl[2][4096];
  __shared__ __align__(16) ushort sBh[2][4096], sBl[2][4096];
  const int tid = threadIdx.x, wid = tid >> 6, lane = tid & 63;
  XCD_SWZ(128, 128)
  const int wm0 = (wid >> 1) * 64, wn0 = (wid & 1) * 64;
  const int fr = lane & 15;
  const int lrow = lane >> 2;
  const int lkc = (lane & 3) ^ ((lane >> 3) & 3);
  const int fpo = fr * 32 + (((lane >> 4) ^ ((lane >> 1) & 3)) * 8);

  f32x4 acc[4][4], accL[4][4];
#pragma unroll
  for (int mi = 0; mi < 4; ++mi)
#pragma unroll
    for (int ni = 0; ni < 4; ++ni)
#pragma unroll
      for (int r = 0; r < 4; ++r) { acc[mi][ni][r] = 0.f; accL[mi][ni][r] = 0.f; }

#pragma unroll
  for (int kk = 0; kk < 2; ++kk) {
    const int kg = kk * 32 + lkc * 8;
#pragma unroll
    for (int i = 0; i < 2; ++i) {
      const int seg = wid * 2 + i;
      const size_t ga = (size_t)(m0 + seg * 16 + lrow) * 64 + kg;
      GLL(&Ah[ga], &sAh[kk][seg * 512]);
      GLL(&Al_[ga], &sAl[kk][seg * 512]);
      const size_t gb = (size_t)(n0 + seg * 16 + lrow) * 64 + kg;
      GLL(&Bh[gb], &sBh[kk][seg * 512]);
      GLL(&Bl[gb], &sBl[kk][seg * 512]);
    }
  }
  __syncthreads();

#pragma unroll
  for (int kk = 0; kk < 2; ++kk) {
    f16x8 ah[4], al[4], bh[4], bl[4];
#pragma unroll
    for (int mi = 0; mi < 4; ++mi) {
      const int r = (wm0 / 16 + mi) * 512 + fpo;
      ah[mi] = *(const f16x8*)&sAh[kk][r];
      al[mi] = *(const f16x8*)&sAl[kk][r];
    }
#pragma unroll
    for (int ni = 0; ni < 4; ++ni) {
      const int r = (wn0 / 16 + ni) * 512 + fpo;
      bh[ni] = *(const f16x8*)&sBh[kk][r];
      bl[ni] = *(const f16x8*)&sBl[kk][r];
    }
#pragma unroll
    for (int mi = 0; mi < 4; ++mi)
#pragma unroll
      for (int ni = 0; ni < 4; ++ni) {
        acc[mi][ni] = __builtin_amdgcn_mfma_f32_16x16x32_f16(ah[mi], bh[ni], acc[mi][ni], 0, 0, 0);
        accL[mi][ni] = __builtin_amdgcn_mfma_f32_16x16x32_f16(al[mi], bh[ni], accL[mi][ni], 0, 0, 0);
        accL[mi][ni] = __builtin_amdgcn_mfma_f32_16x16x32_f16(ah[mi], bl[ni], accL[mi][ni], 0, 0, 0);
      }
  }

#pragma unroll
  for (int ni = 0; ni < 4; ++ni) {
    const int n = n0 + wn0 + ni * 16 + fr;
    const float bv = bias[n];
#pragma unroll
    for (int mi = 0; mi < 4; ++mi)
#pragma unroll
      for (int r = 0; r < 4; ++r) {
        const int m = m0 + wm0 + mi * 16 + (lane >> 4) * 4 + r;
        const float v = splus(acc[mi][ni][r] + accL[mi][ni][r] * (1.f / 2048.f) + bv);
        o[(size_t)m * DIN + n] = split2(v);
      }
  }
}

__device__ __forceinline__ void split_store4h(float4 v, ushort* hi, ushort* lo, size_t i) {
  ushort h0 = f2h(v.x), h1 = f2h(v.y), h2 = f2h(v.z), h3 = f2h(v.w);
  *(ushort4*)&hi[i] = make_ushort4(h0, h1, h2, h3);
  *(ushort4*)&lo[i] = make_ushort4(f2h((v.x - h2f(h0)) * 2048.f), f2h((v.y - h2f(h1)) * 2048.f),
                                   f2h((v.z - h2f(h2)) * 2048.f), f2h((v.w - h2f(h3)) * 2048.f));
}

// One launch converting in_proj_w, hidden, x1w, x2w, dtw1, dtw2 -> f16 planes.
__global__ __launch_bounds__(256) void cvt_fused(const float* __restrict__ inw,
                                                 const float* __restrict__ hid,
                                                 const float* __restrict__ x1w,
                                                 const float* __restrict__ x2w,
                                                 const float* __restrict__ dtw1,
                                                 const float* __restrict__ dtw2,
                                                 ushort* __restrict__ w_hi, ushort* __restrict__ w_lo,
                                                 ushort* __restrict__ h_hi,
                                                 ushort* __restrict__ wx_hi, ushort* __restrict__ wx_lo,
                                                 ushort* __restrict__ dw_hi, ushort* __restrict__ dw_lo) {
  const int q = blockIdx.x * 256 + threadIdx.x;  // float4 index
  if (q >= 1048576 && q < 1572864) {
    const size_t i = (size_t)(q - 1048576) * 4;
    float4 v = *(const float4*)&hid[i];
    *(ushort4*)&h_hi[i] = make_ushort4(f2h(v.x), f2h(v.y), f2h(v.z), f2h(v.w));
    return;
  }
  const float* src; ushort* dhi; ushort* dlo; int base;
  if (q < 1048576)       { src = inw; dhi = w_hi;  dlo = w_lo;  base = q; }
  else if (q < 1622016)  { src = x1w; dhi = wx_hi; dlo = wx_lo; base = q - 1572864; }
  else if (q < 1671168)  { src = x2w; dhi = wx_hi + 196608; dlo = wx_lo + 196608; base = q - 1622016; }
  else if (q < 1703936)  { src = dtw1; dhi = dw_hi; dlo = dw_lo; base = q - 1671168; }
  else                   { src = dtw2; dhi = dw_hi + 131072; dlo = dw_lo + 131072; base = q - 1703936; }
  const size_t i = (size_t)base * 4;
  split_store4h(*(const float4*)&src[i], dhi, dlo, i);
}

__global__ __launch_bounds__(256) void reduce_out(const float* __restrict__ p,
                                                  float* __restrict__ o, int n) {
  const int i = (blockIdx.x * 256 + threadIdx.x) * 4;
  if (i >= n) return;
  float4 a = *(const float4*)&p[i];
  float4 b = *(const float4*)&p[(size_t)n + i];
  float4 c = *(const float4*)&p[(size_t)2 * n + i];
  float4 d = *(const float4*)&p[(size_t)3 * n + i];
  *(float4*)&o[i] = make_float4(a.x + b.x + c.x + d.x, a.y + b.y + c.y + d.y,
                                a.z + b.z + c.z + d.z, a.w + b.w + c.w + d.w);
}

// =====================================================================
// Conv (w=4, causal) + bias + SiLU -> transposed f16 hi/lo planes (l,d).
// Also: silu(z) transposed to (l,d) interleaved ushort2 plane.
// =====================================================================
__global__ __launch_bounds__(256) void conv_tr_kernel(const float* __restrict__ xz,
                                                      const float* __restrict__ cw,
                                                      const float* __restrict__ cb,
                                                      ushort* __restrict__ xcT_hi,
                                                      ushort* __restrict__ xcT_lo,
                                                      ushort2* __restrict__ zs) {
  const int l0 = blockIdx.x * 64, d0 = blockIdx.y * 64;
  const int tid = threadIdx.x;
  __shared__ float xin[64][68];  // cols 0..66 = l0-3 .. l0+63
  __shared__ float To[64][65];
  __shared__ float cwS[64][4];
  __shared__ float cbS[64];

  for (int i = tid; i < 1024; i += 256) {
    const int d = i >> 4, q = i & 15;
    float4 v = *(const float4*)&xz[(size_t)(d0 + d) * SEQ + l0 + q * 4];
    xin[d][3 + q * 4 + 0] = v.x; xin[d][3 + q * 4 + 1] = v.y;
    xin[d][3 + q * 4 + 2] = v.z; xin[d][3 + q * 4 + 3] = v.w;
  }
  if (tid < 192) {
    const int j = tid >> 6, d = tid & 63;
    const int l = l0 - 3 + j;
    xin[d][j] = (l >= 0) ? xz[(size_t)(d0 + d) * SEQ + l] : 0.f;
  }
  if (tid < 64) {
    cbS[tid] = cb[d0 + tid];
    float4 w = *(const float4*)&cw[(d0 + tid) * 4];
    cwS[tid][0] = w.x; cwS[tid][1] = w.y; cwS[tid][2] = w.z; cwS[tid][3] = w.w;
  }
  __syncthreads();

  for (int i = tid; i < 4096; i += 256) {
    const int d = i >> 6, l = i & 63;
    float a = cbS[d] + cwS[d][0] * xin[d][l] + cwS[d][1] * xin[d][l + 1] +
              cwS[d][2] * xin[d][l + 2] + cwS[d][3] * xin[d][l + 3];
    To[d][l] = a / (1.f + __expf(-a));
  }
  __syncthreads();

  for (int i = tid; i < 4096; i += 256) {
    const int l = i >> 6, dd = i & 63;
    float v = To[dd][l];  // stride-65: conflict-free
    ushort h = f2h(v);
    xcT_hi[(size_t)(l0 + l) * DIN + d0 + dd] = h;
    xcT_lo[(size_t)(l0 + l) * DIN + d0 + dd] = f2h((v - h2f(h)) * 2048.f);
  }
  __syncthreads();  // To fully consumed; reuse for z tile

  for (int i = tid; i < 1024; i += 256) {
    const int d = i >> 4, q = i & 15;
    float4 v = *(const float4*)&xz[(size_t)(DIN + d0 + d) * SEQ + l0 + q * 4];
    To[d][q * 4 + 0] = v.x / (1.f + __expf(-v.x));
    To[d][q * 4 + 1] = v.y / (1.f + __expf(-v.y));
    To[d][q * 4 + 2] = v.z / (1.f + __expf(-v.z));
    To[d][q * 4 + 3] = v.w / (1.f + __expf(-v.w));
  }
  __syncthreads();
  for (int i = tid; i < 4096; i += 256) {
    const int l = i >> 6, dd = i & 63;
    zs[(size_t)(l0 + l) * DIN + d0 + dd] = split2(To[dd][l]);
  }
}

// Reduce 16 x_proj split-K slabs (SEQ x 192, l-major) -> B/C tables +
// dt rows as (l,r) f16 hi/lo planes.
__global__ __launch_bounds__(256) void reduce_dblT_kernel(const float* __restrict__ p,
                                                          float* __restrict__ BT1,
                                                          float* __restrict__ CT1,
                                                          float* __restrict__ BT2,
                                                          float* __restrict__ CT2,
                                                          ushort* __restrict__ dtT_hi,
                                                          ushort* __restrict__ dtT_lo) {
  const int NE = SEQ * 192;
  const int idx = blockIdx.x * 256 + threadIdx.x;
  float s = 0.f;
#pragma unroll
  for (int cc = 0; cc < 16; ++cc) s += p[(size_t)cc * NE + idx];
  const int l = idx / 192, k = idx - l * 192;
  if (k < 64) {
    const size_t off = (size_t)l * 64 + k;
    const ushort hh = f2h(s);
    dtT_hi[off] = hh; dtT_lo[off] = f2h((s - h2f(hh)) * 2048.f);
  } else if (k < 80)  BT1[l * NST + (k - 64)] = s;
  else if (k < 96)    CT1[l * NST + (k - 80)] = s;
  else if (k < 160) {
    const size_t off = 131072 + (size_t)l * 64 + (k - 96);
    const ushort hh = f2h(s);
    dtT_hi[off] = hh; dtT_lo[off] = f2h((s - h2f(hh)) * 2048.f);
  }
  else if (k < 176)   BT2[l * NST + (k - 160)] = s;
  else                CT2[l * NST + (k - 176)] = s;
}

// =====================================================================
// Chunked selective scan, BOTH branches fused per thread (u/sp read once).
// sp as interleaved ushort2; u as separate hi/lo planes (GEMM needs them).
// =====================================================================
__global__ __launch_bounds__(256) void scan_phase_a(const ushort* __restrict__ uhi,
                                                    const ushort* __restrict__ ulo,
                                                    const ushort2* __restrict__ sp1,
                                                    const ushort2* __restrict__ sp2,
                                                    const float* __restrict__ BT1,
                                                    const float* __restrict__ BT2,
                                                    const float* __restrict__ Al1,
                                                    const float* __restrict__ Al2,
                                                    float* __restrict__ hend,
                                                    float* __restrict__ Pend) {
  const int c = blockIdx.y, t0 = c * CH;
  const int d = blockIdx.x * 256 + threadIdx.x;
  const size_t gbase = (size_t)t0 * DIN + d;

  __shared__ __align__(16) float Bs[2][CH][NST];
  {
    const int j = threadIdx.x;  // 2*CH*NST floats = 256 float4
    if (j < 128) ((float4*)&Bs[0][0][0])[j] = ((const float4*)&BT1[(size_t)t0 * NST])[j];
    else ((float4*)&Bs[1][0][0])[j - 128] = ((const float4*)&BT2[(size_t)t0 * NST])[j - 128];
  }
  __syncthreads();

  bool fast = true;
#pragma unroll
  for (int n = 0; n < NST; ++n) {
    float k1 = __expf(Al1[(size_t)d * NST + n]);
    float k2 = __expf(Al2[(size_t)d * NST + n]);
    fast = fast && (fabsf(k1 - (float)(n + 1)) < 1e-3f) && (fabsf(k2 - (float)(n + 1)) < 1e-3f);
  }
  float h1[NST], h2[NST];
#pragma unroll
  for (int n = 0; n < NST; ++n) { h1[n] = 0.f; h2[n] = 0.f; }
  float S1 = 0.f, S2 = 0.f;

  if (fast) {
    for (int tt = 0; tt < CH / 4; ++tt) {
      float s1[4], s2[4], ua[4];
#pragma unroll
      for (int j = 0; j < 4; ++j) {
        const size_t idx = gbase + (size_t)(tt * 4 + j) * DIN;
        s1[j] = join2(sp1[idx]);
        s2[j] = join2(sp2[idx]);
        ua[j] = h2f(uhi[idx]) + h2f(ulo[idx]) * (1.f / 2048.f);
      }
#pragma unroll
      for (int j = 0; j < 4; ++j) {
        const int t = tt * 4 + j;
        S1 += s1[j]; S2 += s2[j];
        const float spu1 = s1[j] * ua[j], spu2 = s2[j] * ua[j];
        float p[NST];
        powers16(__expf(-s1[j]), p);
#pragma unroll
        for (int n = 0; n < NST; ++n) h1[n] = fmaf(p[n], h1[n], spu1 * Bs[0][t][n]);
        powers16(__expf(-s2[j]), p);
#pragma unroll
        for (int n = 0; n < NST; ++n) h2[n] = fmaf(p[n], h2[n], spu2 * Bs[1][t][n]);
      }
    }
  } else {
    float A1e[NST], A2e[NST];
#pragma unroll
    for (int n = 0; n < NST; ++n) {
      A1e[n] = -__expf(Al1[(size_t)d * NST + n]) * LOG2E;
      A2e[n] = -__expf(Al2[(size_t)d * NST + n]) * LOG2E;
    }
    for (int tt = 0; tt < CH / 4; ++tt) {
      float s1[4], s2[4], ua[4];
#pragma unroll
      for (int j = 0; j < 4; ++j) {
        const size_t idx = gbase + (size_t)(tt * 4 + j) * DIN;
        s1[j] = join2(sp1[idx]);
        s2[j] = join2(sp2[idx]);
        ua[j] = h2f(uhi[idx]) + h2f(ulo[idx]) * (1.f / 2048.f);
      }
#pragma unroll
      for (int j = 0; j < 4; ++j) {
        const int t = tt * 4 + j;
        S1 += s1[j]; S2 += s2[j];
        const float spu1 = s1[j] * ua[j], spu2 = s2[j] * ua[j];
#pragma unroll
        for (int n = 0; n < NST; ++n) {
          h1[n] = fmaf(exp2f(A1e[n] * s1[j]), h1[n], spu1 * Bs[0][t][n]);
          h2[n] = fmaf(exp2f(A2e[n] * s2[j]), h2[n], spu2 * Bs[1][t][n]);
        }
      }
    }
  }

  float P1[NST], P2[NST];
  if (fast) {
    powers16(__expf(-S1), P1);
    powers16(__expf(-S2), P2);
  } else {
#pragma unroll
    for (int n = 0; n < NST; ++n) {
      P1[n] = exp2f(-__expf(Al1[(size_t)d * NST + n]) * LOG2E * S1);
      P2[n] = exp2f(-__expf(Al2[(size_t)d * NST + n]) * LOG2E * S2);
    }
  }
  const size_t b1 = ((size_t)c * DIN + d) * NST;
  const size_t b2 = ((size_t)(NCH + c) * DIN + d) * NST;
#pragma unroll
  for (int n = 0; n < NST; n += 4) {
    *(float4*)&hend[b1 + n] = make_float4(h1[n], h1[n + 1], h1[n + 2], h1[n + 3]);
    *(float4*)&Pend[b1 + n] = make_float4(P1[n], P1[n + 1], P1[n + 2], P1[n + 3]);
    *(float4*)&hend[b2 + n] = make_float4(h2[n], h2[n + 1], h2[n + 2], h2[n + 3]);
    *(float4*)&Pend[b2 + n] = make_float4(P2[n], P2[n + 1], P2[n + 2], P2[n + 3]);
  }
}

// Merged: blocks [0,256) do the chunk-carry (hin overwrites Pend in place,
// software-pipelined: loads for chunk c+1 issue before the store/fma of c);
// blocks [256,2304) convert outw -> f16 hi plane.
__global__ __launch_bounds__(256) void carry_cvt(const float* __restrict__ hend,
                                                 float* __restrict__ PendHin,
                                                 const float* __restrict__ outw,
                                                 ushort* __restrict__ ow_hi) {
  const int b = blockIdx.x;
  if (b < 256) {
    const int flat = b * 256 + threadIdx.x;
    const int br = flat >> 15;
    const int dn = flat & 32767;
    size_t idx = ((size_t)(br * NCH) << 15) + dn;
    float h = 0.f;
    float Pv = PendHin[idx];
    float he = hend[idx];
    for (int c = 0; c < NCH; ++c) {
      const size_t nidx = idx + (1u << 15);
      float Pn = 0.f, hn = 0.f;
      if (c + 1 < NCH) { Pn = PendHin[nidx]; hn = hend[nidx]; }
      PendHin[idx] = h;
      h = fmaf(Pv, h, he);
      Pv = Pn; he = hn; idx = nidx;
    }
  } else {
    const size_t i = ((size_t)(b - 256) * 256 + threadIdx.x) * 4;  // < 2,097,152
    float4 v = *(const float4*)&outw[i];
    *(ushort4*)&ow_hi[i] = make_ushort4(f2h(v.x), f2h(v.y), f2h(v.z), f2h(v.w));
  }
}

// Phase C fused: both branches per thread; emits yd = (y1-y2+(D1-D2)u)*silu(z)
// directly as f16 hi/lo planes IN PLACE over the u planes.
__global__ __launch_bounds__(256) void scan_phase_c(const ushort* __restrict__ uhi,
                                                    const ushort* __restrict__ ulo,
                                                    const ushort2* __restrict__ sp1,
                                                    const ushort2* __restrict__ sp2,
                                                    const float* __restrict__ BT1,
                                                    const float* __restrict__ CT1,
                                                    const float* __restrict__ BT2,
                                                    const float* __restrict__ CT2,
                                                    const float* __restrict__ Al1,
                                                    const float* __restrict__ Al2,
                                                    const float* __restrict__ D1,
                                                    const float* __restrict__ D2,
                                                    const float* __restrict__ hin,
                                                    const ushort2* __restrict__ zs,
                                                    ushort* __restrict__ yd_hi,
                                                    ushort* __restrict__ yd_lo) {
  const int c = blockIdx.y, t0 = c * CH;
  const int d = blockIdx.x * 256 + threadIdx.x;
  const size_t gbase = (size_t)t0 * DIN + d;

  __shared__ __align__(16) float Bs[2][CH][NST];
  __shared__ __align__(16) float Cs[2][CH][NST];
  {
    const int j = threadIdx.x;
    if (j < 128) {
      ((float4*)&Bs[0][0][0])[j] = ((const float4*)&BT1[(size_t)t0 * NST])[j];
      ((float4*)&Cs[0][0][0])[j] = ((const float4*)&CT1[(size_t)t0 * NST])[j];
    } else {
      ((float4*)&Bs[1][0][0])[j - 128] = ((const float4*)&BT2[(size_t)t0 * NST])[j - 128];
      ((float4*)&Cs[1][0][0])[j - 128] = ((const float4*)&CT2[(size_t)t0 * NST])[j - 128];
    }
  }
  __syncthreads();

  bool fast = true;
#pragma unroll
  for (int n = 0; n < NST; ++n) {
    float k1 = __expf(Al1[(size_t)d * NST + n]);
    float k2 = __expf(Al2[(size_t)d * NST + n]);
    fast = fast && (fabsf(k1 - (float)(n + 1)) < 1e-3f) && (fabsf(k2 - (float)(n + 1)) < 1e-3f);
  }
  const float Ddd = D1[d] - D2[d];
  float h1[NST], h2[NST];
  const size_t hb1 = ((size_t)c * DIN + d) * NST;
  const size_t hb2 = ((size_t)(NCH + c) * DIN + d) * NST;
#pragma unroll
  for (int n = 0; n < NST; n += 4) {
    float4 v1 = *(const float4*)&hin[hb1 + n];
    h1[n] = v1.x; h1[n + 1] = v1.y; h1[n + 2] = v1.z; h1[n + 3] = v1.w;
    float4 v2 = *(const float4*)&hin[hb2 + n];
    h2[n] = v2.x; h2[n + 1] = v2.y; h2[n + 2] = v2.z; h2[n + 3] = v2.w;
  }

  if (fast) {
    for (int tt = 0; tt < CH / 4; ++tt) {
      float s1[4], s2[4], ua[4];
#pragma unroll
      for (int j = 0; j < 4; ++j) {
        const size_t idx = gbase + (size_t)(tt * 4 + j) * DIN;
        s1[j] = join2(sp1[idx]);
        s2[j] = join2(sp2[idx]);
        ua[j] = h2f(uhi[idx]) + h2f(ulo[idx]) * (1.f / 2048.f);
      }
#pragma unroll
      for (int j = 0; j < 4; ++j) {
        const int t = tt * 4 + j;
        const size_t idx = gbase + (size_t)t * DIN;
        const float spu1 = s1[j] * ua[j], spu2 = s2[j] * ua[j];
        float p[NST];
        float y1 = 0.f, y2 = 0.f;
        powers16(__expf(-s1[j]), p);
#pragma unroll
        for (int n = 0; n < NST; ++n) {
          h1[n] = fmaf(p[n], h1[n], spu1 * Bs[0][t][n]);
          y1 = fmaf(h1[n], Cs[0][t][n], y1);
        }
        powers16(__expf(-s2[j]), p);
#pragma unroll
        for (int n = 0; n < NST; ++n) {
          h2[n] = fmaf(p[n], h2[n], spu2 * Bs[1][t][n]);
          y2 = fmaf(h2[n], Cs[1][t][n], y2);
        }
        const float zv = join2(zs[idx]);
        const float yd = (y1 - y2 + Ddd * ua[j]) * zv;
        const ushort hh = f2h(yd);
        yd_hi[idx] = hh;
        yd_lo[idx] = f2h((yd - h2f(hh)) * 2048.f);
      }
    }
  } else {
    float A1e[NST], A2e[NST];
#pragma unroll
    for (int n = 0; n < NST; ++n) {
      A1e[n] = -__expf(Al1[(size_t)d * NST + n]) * LOG2E;
      A2e[n] = -__expf(Al2[(size_t)d * NST + n]) * LOG2E;
    }
    for (int tt = 0; tt < CH / 4; ++tt) {
      float s1[4], s2[4], ua[4];
#pragma unroll
      for (int j = 0; j < 4; ++j) {
        const size_t idx = gbase + (size_t)(tt * 4 + j) * DIN;
        s1[j] = join2(sp1[idx]);
        s2[j] = join2(sp2[idx]);
        ua[j] = h2f(uhi[idx]) + h2f(ulo[idx]) * (1.f / 2048.f);
      }
#pragma unroll
      for (int j = 0; j < 4; ++j) {
        const int t = tt * 4 + j;
        const size_t idx = gbase + (size_t)t * DIN;
        const float spu1 = s1[j] * ua[j], spu2 = s2[j] * ua[j];
        float y1 = 0.f, y2 = 0.f;
#pragma unroll
        for (int n = 0; n < NST; ++n) {
          h1[n] = fmaf(exp2f(A1e[n] * s1[j]), h1[n], spu1 * Bs[0][t][n]);
          y1 = fmaf(h1[n], Cs[0][t][n], y1);
          h2[n] = fmaf(exp2f(A2e[n] * s2[j]), h2[n], spu2 * Bs[1][t][n]);
          y2 = fmaf(h2[n], Cs[1][t][n], y2);
        }
        const float zv = join2(zs[idx]);
        const float yd = (y1 - y2 + Ddd * ua[j]) * zv;
        const ushort hh = f2h(yd);
        yd_hi[idx] = hh;
        yd_lo[idx] = f2h((yd - h2f(hh)) * 2048.f);
      }
    }
  }
}

// =====================================================================
extern "C" void kernel_launch(void* const* d_in, const int* in_sizes, int n_in,
                              void* d_out, int out_size, void* d_ws, size_t ws_size,
                              hipStream_t stream) {
  const float* hidden = (const float*)d_in[0];
  const float* in_proj_w = (const float*)d_in[1];
  const float* conv_w = (const float*)d_in[2];
  const float* conv_b = (const float*)d_in[3];
  const float* x1w = (const float*)d_in[4];
  const float* dtw1 = (const float*)d_in[5];
  const float* dtb1 = (const float*)d_in[6];
  const float* Al1 = (const float*)d_in[7];
  const float* D1 = (const float*)d_in[8];
  const float* x2w = (const float*)d_in[9];
  const float* dtw2 = (const float*)d_in[10];
  const float* dtb2 = (const float*)d_in[11];
  const float* Al2 = (const float*)d_in[12];
  const float* D2 = (const float*)d_in[13];
  const float* outw = (const float*)d_in[14];
  float* out = (float*)d_out;

  // Workspace layout (floats), same 34.47M footprint.
  float* ws = (float*)d_ws;
  float* xz = ws;                                    // 8.39M  (x rows, z rows)
  float* xcTbuf = xz + (size_t)4096 * SEQ;           // 4.19M  u f16 hi/lo planes
  float* dtTbuf = xcTbuf + (size_t)SEQ * DIN;        // 393K   dtT f16 hi/lo planes
  float* spbuf1 = dtTbuf + (size_t)192 * SEQ;        // 4.19M  sp1 ushort2 plane
  float* spbuf2 = spbuf1 + (size_t)SEQ * DIN;        // 4.19M  sp2 ushort2 plane
  float* zsbuf = spbuf2 + (size_t)SEQ * DIN;         // 4.19M  silu(z) ushort2 plane
  float* hendB = zsbuf + (size_t)SEQ * DIN;          // 4.19M
  float* PendB = hendB + (size_t)2 * NCH * DIN * NST;// 4.19M
  float* BT1 = PendB + (size_t)2 * NCH * DIN * NST;  // 32K each
  float* CT1 = BT1 + (size_t)SEQ * NST;
  float* BT2 = CT1 + (size_t)SEQ * NST;
  float* CT2 = BT2 + (size_t)SEQ * NST;
  float* wxp = CT2 + (size_t)SEQ * NST;              // 393K stacked x_proj W planes

  // Aliases (lifetime-disjoint):
  ushort* xcT_hi = (ushort*)xcTbuf;                  // u planes, steps 3..scan C
  ushort* xcT_lo = (ushort*)(xcTbuf + 2097152);
  ushort* dtT_hi = (ushort*)dtTbuf;                  // dt rows (l,64) x 2 branches
  ushort* dtT_lo = dtT_hi + 262144;
  ushort2* sp1 = (ushort2*)spbuf1;                   // interleaved sp planes
  ushort2* sp2 = (ushort2*)spbuf2;
  ushort2* zs = (ushort2*)zsbuf;                     // interleaved silu(z) plane
  ushort* w_hi = (ushort*)zsbuf;                     // in_proj_w planes (dead after step 2,
  ushort* w_lo = (ushort*)(zsbuf + 2097152);         //   before conv writes zs plane)
  ushort* h_hi = (ushort*)hendB;                     // hidden hi plane (dead after step 2)
  ushort* dw_hi = ((ushort*)hendB) + 2097152;        // dtw planes behind h_hi (dead
  ushort* dw_lo = dw_hi + 262144;                    //   before scan_a writes hendB)
  ushort* wx_hi = (ushort*)wxp;                      // stacked x_proj weights 192x2048
  ushort* wx_lo = (ushort*)(wxp + 196608);
  float* xp_part = spbuf1;                           // 16 slabs x SEQ*192*4B = 25.2MB,
                                                     //   spans spbuf1+spbuf2 (sp written later)
  ushort* yd_hi = (ushort*)xcTbuf;                   // yd planes overwrite u in-place
  ushort* yd_lo = (ushort*)(xcTbuf + 2097152);
  ushort* ow_hi = (ushort*)xz;                       // outw hi plane in dead xz
  float* opart = spbuf1;                             // out_proj partials: 33.6MB spans
                                                     //   spbuf1+spbuf2 (sp dead by then)
  dim3 blk(256);

  // 1) fused split-convert: in_proj_w, hidden (hi only), x1w, x2w, dtw1, dtw2
  cvt_fused<<<dim3(6784), blk, 0, stream>>>(in_proj_w, hidden, x1w, x2w, dtw1, dtw2,
                                            w_hi, w_lo, h_hi, wx_hi, wx_lo, dw_hi, dw_lo);

  // 2) in_proj via f16 MFMA 2-pass (dual-32 stages) -> xz (e,l)
  gemm3p<128, 128, 1, 2><<<dim3(SEQ / 128, 4096 / 128, 1), blk, 0, stream>>>(
      w_hi, w_lo, h_hi, h_hi, xz, 4096, SEQ, DMODEL);

  // 3) conv + silu -> u f16 planes (l,d); silu(z) -> ushort2 plane (l,d)
  conv_tr_kernel<<<dim3(SEQ / 64, DIN / 64), blk, 0, stream>>>(
      xz, conv_w, conv_b, xcT_hi, xcT_lo, zs);

  // 4) x_proj swapped: C[l, k(192)] = sum_d xcT[l,d]*wx[k,d], split-K=16
  gemm3p<128, 64, 16, 0><<<dim3(192 / 64, SEQ / 128, 16), blk, 0, stream>>>(
      xcT_hi, xcT_lo, wx_hi, wx_lo, xp_part, SEQ, 192, DIN);

  // 5) reduce 16 slabs -> B/C tables + dtT f16 planes
  reduce_dblT_kernel<<<dim3(192 * SEQ / 256), blk, 0, stream>>>(
      xp_part, BT1, CT1, BT2, CT2, dtT_hi, dtT_lo);

  // 6) dt projection on MFMA (K=64, one dual-stage) -> sp ushort2 planes
  dt_mfma<<<dim3(DIN / 128, SEQ / 128, 2), blk, 0, stream>>>(
      dtT_hi, dtT_lo, dw_hi, dw_lo, dtb1, dtb2, sp1, sp2);

  // 7) chunked scan (A, carry+cvt, C)
  scan_phase_a<<<dim3(DIN / 256, NCH), blk, 0, stream>>>(
      xcT_hi, xcT_lo, sp1, sp2, BT1, BT2, Al1, Al2, hendB, PendB);
  carry_cvt<<<dim3(2304), blk, 0, stream>>>(hendB, PendB, outw, ow_hi);
  scan_phase_c<<<dim3(DIN / 256, NCH), blk, 0, stream>>>(
      xcT_hi, xcT_lo, sp1, sp2, BT1, CT1, BT2, CT2, Al1, Al2,
      D1, D2, PendB, zs, yd_hi, yd_lo);

  // 8) out_proj via f16 MFMA 2-pass (dual-32 stages), split-K=4
  gemm3p<128, 128, 4, 2><<<dim3(DMODEL / 128, SEQ / 128, 4), blk, 0, stream>>>(
      yd_hi, yd_lo, ow_hi, ow_hi, opart, SEQ, DMODEL, DIN);
  reduce_out<<<dim3(SEQ * DMODEL / 1024), blk, 0, stream>>>(opart, out, SEQ * DMODEL);
}

// Round 11
// 306.530 us; speedup vs baseline: 1.2907x; 1.0770x over previous
//
#include <hip/hip_runtime.h>
#include <math.h>

#define SEQ 2048
#define DMODEL 1024
#define DIN 2048
#define NST 16
#define DTR 64
#define CH 32
#define NCH (SEQ / CH)
#define LOG2E 1.4426950408889634f

typedef __attribute__((ext_vector_type(8))) _Float16 f16x8;
typedef __attribute__((ext_vector_type(4))) float f32x4;

// f16 split (11-bit mantissa): hi = f16(v), lo = f16((v-hi)*2048).
// hi + lo*2^-11 reconstructs to ~2^-22 relative: NOT a precision cut.
__device__ __forceinline__ ushort f2h(float f) {
  union { _Float16 h; ushort u; } c; c.h = (_Float16)f; return c.u;
}
__device__ __forceinline__ float h2f(ushort u) {
  union { ushort u; _Float16 h; } c; c.u = u; return (float)c.h;
}
__device__ __forceinline__ ushort2 split2(float v) {
  ushort hh = f2h(v);
  return make_ushort2(hh, f2h((v - h2f(hh)) * 2048.f));
}
__device__ __forceinline__ float join2(ushort2 p) {
  return h2f(p.x) + h2f(p.y) * (1.f / 2048.f);
}
// Fast softplus: max(v,0) + log(1+exp(-|v|)) on HW v_log/v_exp
// (abs err ~2^-23; replaces libm log1pf which dominated dt VALU).
__device__ __forceinline__ float splus(float v) {
  return fmaxf(v, 0.f) + __logf(1.f + __expf(-fabsf(v)));
}
// p[n] = e^(n+1), depth-4 mul tree (no transcendentals).
__device__ __forceinline__ void powers16(float e, float* p) {
  float e2 = e * e, e4 = e2 * e2, e8 = e4 * e4;
  p[0] = e;       p[1] = e2;       p[2] = e2 * e;   p[3] = e4;
  p[4] = e4 * e;  p[5] = e4 * e2;  p[6] = e4 * p[2]; p[7] = e8;
  p[8] = e8 * e;  p[9] = e8 * e2;  p[10] = e8 * p[2]; p[11] = e8 * e4;
  p[12] = e8 * p[4]; p[13] = e8 * p[5]; p[14] = e8 * p[6]; p[15] = e8 * e8;
}

#define GLL(g, l) __builtin_amdgcn_global_load_lds( \
    (const __attribute__((address_space(1))) void*)(g), \
    (__attribute__((address_space(3))) void*)(l), 16, 0, 0)

// Bijective XCD swizzle over the (x,y) grid; requires nwg_xy % 8 == 0.
#define XCD_SWZ(BMv, BNv)                                              \
  const int nwg_ = gridDim.x * gridDim.y;                              \
  const int flat_ = blockIdx.y * gridDim.x + blockIdx.x;               \
  const int swz_ = (flat_ & 7) * (nwg_ >> 3) + (flat_ >> 3);           \
  const int m0 = (swz_ / gridDim.x) * (BMv);                           \
  const int n0 = (swz_ % gridDim.x) * (BNv);

// =====================================================================
// Split-f16 MFMA GEMM (round-6 proven dual-32-stage version).
// MODE 0: 3-pass; MODE 2: 2-pass (B_lo dropped).
// C = acc + accL * 2^-11 (lo planes stored pre-scaled x2048).
// =====================================================================
template<int BM, int BN, int SPLITK, int MODE>
__global__ __launch_bounds__(256, 2) void gemm3p(const ushort* __restrict__ Ahi,
                                                 const ushort* __restrict__ Alo,
                                                 const ushort* __restrict__ Bhi,
                                                 const ushort* __restrict__ Blo,
                                                 float* __restrict__ C,
                                                 int M, int N, int K) {
  constexpr int WM = BM / 2, WN = BN / 2, TM = WM / 16, TN = WN / 16;
  constexpr int SA = BM / 16, SB = BN / 16;
  constexpr bool dropB = (MODE == 2);
  __shared__ __align__(16) ushort sAh[2][BM * 32], sAl[2][BM * 32];
  __shared__ __align__(16) ushort sBh[2][BN * 32];
  __shared__ __align__(16) ushort sBl[2][dropB ? 16 : BN * 32];
  const int tid = threadIdx.x, wid = tid >> 6, lane = tid & 63;
  XCD_SWZ(BM, BN)
  const int Kc = K / SPLITK, kbeg = blockIdx.z * Kc;
  const int wm0 = (wid >> 1) * WM, wn0 = (wid & 1) * WN;
  const int fr = lane & 15;
  const int lrow = lane >> 2;
  const int lkc = (lane & 3) ^ ((lane >> 3) & 3);
  const int fpo = fr * 32 + (((lane >> 4) ^ ((lane >> 1) & 3)) * 8);

  f32x4 acc[TM][TN], accL[TM][TN];
#pragma unroll
  for (int mi = 0; mi < TM; ++mi)
#pragma unroll
    for (int ni = 0; ni < TN; ++ni)
#pragma unroll
      for (int r = 0; r < 4; ++r) { acc[mi][ni][r] = 0.f; accL[mi][ni][r] = 0.f; }

  for (int k0 = 0; k0 < Kc; k0 += 64) {
    __syncthreads();
#pragma unroll
    for (int kk = 0; kk < 2; ++kk) {
      const int kg = kbeg + k0 + kk * 32 + lkc * 8;
#pragma unroll
      for (int i = 0; i < SA / 4; ++i) {
        const int seg = wid * (SA / 4) + i;
        const size_t ga = (size_t)(m0 + seg * 16 + lrow) * K + kg;
        GLL(&Ahi[ga], &sAh[kk][seg * 512]);
        GLL(&Alo[ga], &sAl[kk][seg * 512]);
      }
#pragma unroll
      for (int i = 0; i < SB / 4; ++i) {
        const int seg = wid * (SB / 4) + i;
        const size_t ga = (size_t)(n0 + seg * 16 + lrow) * K + kg;
        GLL(&Bhi[ga], &sBh[kk][seg * 512]);
        if constexpr (!dropB) GLL(&Blo[ga], &sBl[kk][seg * 512]);
      }
    }
    __syncthreads();

#pragma unroll
    for (int kk = 0; kk < 2; ++kk) {
      f16x8 ah[TM], al[TM], bh[TN], bl[TN];
#pragma unroll
      for (int mi = 0; mi < TM; ++mi) {
        const int r = (wm0 / 16 + mi) * 512 + fpo;
        ah[mi] = *(const f16x8*)&sAh[kk][r];
        al[mi] = *(const f16x8*)&sAl[kk][r];
      }
#pragma unroll
      for (int ni = 0; ni < TN; ++ni) {
        const int r = (wn0 / 16 + ni) * 512 + fpo;
        bh[ni] = *(const f16x8*)&sBh[kk][r];
        if constexpr (!dropB) bl[ni] = *(const f16x8*)&sBl[kk][r];
      }
#pragma unroll
      for (int mi = 0; mi < TM; ++mi)
#pragma unroll
        for (int ni = 0; ni < TN; ++ni) {
          acc[mi][ni] = __builtin_amdgcn_mfma_f32_16x16x32_f16(ah[mi], bh[ni], acc[mi][ni], 0, 0, 0);
          accL[mi][ni] = __builtin_amdgcn_mfma_f32_16x16x32_f16(al[mi], bh[ni], accL[mi][ni], 0, 0, 0);
          if constexpr (!dropB)
            accL[mi][ni] = __builtin_amdgcn_mfma_f32_16x16x32_f16(ah[mi], bl[ni], accL[mi][ni], 0, 0, 0);
        }
    }
  }

  float* __restrict__ Co = C + (size_t)blockIdx.z * M * N;
#pragma unroll
  for (int mi = 0; mi < TM; ++mi)
#pragma unroll
    for (int ni = 0; ni < TN; ++ni)
#pragma unroll
      for (int r = 0; r < 4; ++r)
        Co[(size_t)(m0 + wm0 + mi * 16 + (lane >> 4) * 4 + r) * N + n0 + wn0 + ni * 16 + fr] =
            acc[mi][ni][r] + accL[mi][ni][r] * (1.f / 2048.f);
}

// =====================================================================
// dt projection on MFMA, SWAPPED operands: C[d][l] = sum_k dtw[d,k]*dtT[l,k]
// (A = dw rows d, B = dtT rows l).  The C fragment's register index r walks
// 4 CONSECUTIVE d -> epilogue packs 4 ushort2 into ONE 16B store at
// sp[l*DIN+d] (r10 counters: old scattered-4B epilogue + log1pf = 42us,
// 7x over its ~6us roofline).  K=64 = one dual-32 stage.
// =====================================================================
__global__ __launch_bounds__(256, 2) void dt_mfma(const ushort* __restrict__ dtT_hi,
                                                  const ushort* __restrict__ dtT_lo,
                                                  const ushort* __restrict__ dw_hi,
                                                  const ushort* __restrict__ dw_lo,
                                                  const float* __restrict__ b1,
                                                  const float* __restrict__ b2,
                                                  ushort2* __restrict__ sp1,
                                                  ushort2* __restrict__ sp2) {
  const int br = blockIdx.z;
  const ushort* __restrict__ Ah = dw_hi + (size_t)br * 131072;   // A = dtw (d rows)
  const ushort* __restrict__ Al_ = dw_lo + (size_t)br * 131072;
  const ushort* __restrict__ Bh = dtT_hi + (size_t)br * 131072;  // B = dtT (l rows)
  const ushort* __restrict__ Bl = dtT_lo + (size_t)br * 131072;
  const float* __restrict__ bias = br ? b2 : b1;
  ushort2* __restrict__ o = br ? sp2 : sp1;
  __shared__ __align__(16) ushort sAh[2][4096], sAl[2][4096];
  __shared__ __align__(16) ushort sBh[2][4096], sBl[2][4096];
  const int tid = threadIdx.x, wid = tid >> 6, lane = tid & 63;
  XCD_SWZ(128, 128)   // m0 -> d tile, n0 -> l tile
  const int wm0 = (wid >> 1) * 64, wn0 = (wid & 1) * 64;
  const int fr = lane & 15;
  const int lrow = lane >> 2;
  const int lkc = (lane & 3) ^ ((lane >> 3) & 3);
  const int fpo = fr * 32 + (((lane >> 4) ^ ((lane >> 1) & 3)) * 8);

  f32x4 acc[4][4], accL[4][4];
#pragma unroll
  for (int mi = 0; mi < 4; ++mi)
#pragma unroll
    for (int ni = 0; ni < 4; ++ni)
#pragma unroll
      for (int r = 0; r < 4; ++r) { acc[mi][ni][r] = 0.f; accL[mi][ni][r] = 0.f; }

#pragma unroll
  for (int kk = 0; kk < 2; ++kk) {
    const int kg = kk * 32 + lkc * 8;
#pragma unroll
    for (int i = 0; i < 2; ++i) {
      const int seg = wid * 2 + i;
      const size_t ga = (size_t)(m0 + seg * 16 + lrow) * 64 + kg;
      GLL(&Ah[ga], &sAh[kk][seg * 512]);
      GLL(&Al_[ga], &sAl[kk][seg * 512]);
      const size_t gb = (size_t)(n0 + seg * 16 + lrow) * 64 + kg;
      GLL(&Bh[gb], &sBh[kk][seg * 512]);
      GLL(&Bl[gb], &sBl[kk][seg * 512]);
    }
  }
  __syncthreads();

#pragma unroll
  for (int kk = 0; kk < 2; ++kk) {
    f16x8 ah[4], al[4], bh[4], bl[4];
#pragma unroll
    for (int mi = 0; mi < 4; ++mi) {
      const int r = (wm0 / 16 + mi) * 512 + fpo;
      ah[mi] = *(const f16x8*)&sAh[kk][r];
      al[mi] = *(const f16x8*)&sAl[kk][r];
    }
#pragma unroll
    for (int ni = 0; ni < 4; ++ni) {
      const int r = (wn0 / 16 + ni) * 512 + fpo;
      bh[ni] = *(const f16x8*)&sBh[kk][r];
      bl[ni] = *(const f16x8*)&sBl[kk][r];
    }
#pragma unroll
    for (int mi = 0; mi < 4; ++mi)
#pragma unroll
      for (int ni = 0; ni < 4; ++ni) {
        acc[mi][ni] = __builtin_amdgcn_mfma_f32_16x16x32_f16(ah[mi], bh[ni], acc[mi][ni], 0, 0, 0);
        accL[mi][ni] = __builtin_amdgcn_mfma_f32_16x16x32_f16(al[mi], bh[ni], accL[mi][ni], 0, 0, 0);
        accL[mi][ni] = __builtin_amdgcn_mfma_f32_16x16x32_f16(ah[mi], bl[ni], accL[mi][ni], 0, 0, 0);
      }
  }

  // Epilogue: 16B stores (4 consecutive d per fragment).
#pragma unroll
  for (int mi = 0; mi < 4; ++mi) {
    const int dbase = m0 + wm0 + mi * 16 + (lane >> 4) * 4;
    const float4 b4 = *(const float4*)&bias[dbase];
    const float bv[4] = {b4.x, b4.y, b4.z, b4.w};
#pragma unroll
    for (int ni = 0; ni < 4; ++ni) {
      const int l = n0 + wn0 + ni * 16 + fr;
      uint pk[4];
#pragma unroll
      for (int r = 0; r < 4; ++r) {
        const ushort2 s = split2(splus(acc[mi][ni][r] + accL[mi][ni][r] * (1.f / 2048.f) + bv[r]));
        pk[r] = (uint)s.x | ((uint)s.y << 16);
      }
      *(uint4*)&o[(size_t)l * DIN + dbase] = make_uint4(pk[0], pk[1], pk[2], pk[3]);
    }
  }
}

__device__ __forceinline__ void split_store4h(float4 v, ushort* hi, ushort* lo, size_t i) {
  ushort h0 = f2h(v.x), h1 = f2h(v.y), h2 = f2h(v.z), h3 = f2h(v.w);
  *(ushort4*)&hi[i] = make_ushort4(h0, h1, h2, h3);
  *(ushort4*)&lo[i] = make_ushort4(f2h((v.x - h2f(h0)) * 2048.f), f2h((v.y - h2f(h1)) * 2048.f),
                                   f2h((v.z - h2f(h2)) * 2048.f), f2h((v.w - h2f(h3)) * 2048.f));
}

// One launch converting in_proj_w, hidden, x1w, x2w, dtw1, dtw2 -> f16 planes.
__global__ __launch_bounds__(256) void cvt_fused(const float* __restrict__ inw,
                                                 const float* __restrict__ hid,
                                                 const float* __restrict__ x1w,
                                                 const float* __restrict__ x2w,
                                                 const float* __restrict__ dtw1,
                                                 const float* __restrict__ dtw2,
                                                 ushort* __restrict__ w_hi, ushort* __restrict__ w_lo,
                                                 ushort* __restrict__ h_hi,
                                                 ushort* __restrict__ wx_hi, ushort* __restrict__ wx_lo,
                                                 ushort* __restrict__ dw_hi, ushort* __restrict__ dw_lo) {
  const int q = blockIdx.x * 256 + threadIdx.x;  // float4 index
  if (q >= 1048576 && q < 1572864) {
    const size_t i = (size_t)(q - 1048576) * 4;
    float4 v = *(const float4*)&hid[i];
    *(ushort4*)&h_hi[i] = make_ushort4(f2h(v.x), f2h(v.y), f2h(v.z), f2h(v.w));
    return;
  }
  const float* src; ushort* dhi; ushort* dlo; int base;
  if (q < 1048576)       { src = inw; dhi = w_hi;  dlo = w_lo;  base = q; }
  else if (q < 1622016)  { src = x1w; dhi = wx_hi; dlo = wx_lo; base = q - 1572864; }
  else if (q < 1671168)  { src = x2w; dhi = wx_hi + 196608; dlo = wx_lo + 196608; base = q - 1622016; }
  else if (q < 1703936)  { src = dtw1; dhi = dw_hi; dlo = dw_lo; base = q - 1671168; }
  else                   { src = dtw2; dhi = dw_hi + 131072; dlo = dw_lo + 131072; base = q - 1703936; }
  const size_t i = (size_t)base * 4;
  split_store4h(*(const float4*)&src[i], dhi, dlo, i);
}

__global__ __launch_bounds__(256) void reduce_out(const float* __restrict__ p,
                                                  float* __restrict__ o, int n) {
  const int i = (blockIdx.x * 256 + threadIdx.x) * 4;
  if (i >= n) return;
  float4 a = *(const float4*)&p[i];
  float4 b = *(const float4*)&p[(size_t)n + i];
  float4 c = *(const float4*)&p[(size_t)2 * n + i];
  float4 d = *(const float4*)&p[(size_t)3 * n + i];
  *(float4*)&o[i] = make_float4(a.x + b.x + c.x + d.x, a.y + b.y + c.y + d.y,
                                a.z + b.z + c.z + d.z, a.w + b.w + c.w + d.w);
}

// =====================================================================
// Conv (w=4, causal) + bias + SiLU -> transposed f16 hi/lo planes (l,d).
// Also: silu(z) transposed to (l,d) interleaved ushort2 plane.
// =====================================================================
__global__ __launch_bounds__(256) void conv_tr_kernel(const float* __restrict__ xz,
                                                      const float* __restrict__ cw,
                                                      const float* __restrict__ cb,
                                                      ushort* __restrict__ xcT_hi,
                                                      ushort* __restrict__ xcT_lo,
                                                      ushort2* __restrict__ zs) {
  const int l0 = blockIdx.x * 64, d0 = blockIdx.y * 64;
  const int tid = threadIdx.x;
  __shared__ float xin[64][68];  // cols 0..66 = l0-3 .. l0+63
  __shared__ float To[64][65];
  __shared__ float cwS[64][4];
  __shared__ float cbS[64];

  for (int i = tid; i < 1024; i += 256) {
    const int d = i >> 4, q = i & 15;
    float4 v = *(const float4*)&xz[(size_t)(d0 + d) * SEQ + l0 + q * 4];
    xin[d][3 + q * 4 + 0] = v.x; xin[d][3 + q * 4 + 1] = v.y;
    xin[d][3 + q * 4 + 2] = v.z; xin[d][3 + q * 4 + 3] = v.w;
  }
  if (tid < 192) {
    const int j = tid >> 6, d = tid & 63;
    const int l = l0 - 3 + j;
    xin[d][j] = (l >= 0) ? xz[(size_t)(d0 + d) * SEQ + l] : 0.f;
  }
  if (tid < 64) {
    cbS[tid] = cb[d0 + tid];
    float4 w = *(const float4*)&cw[(d0 + tid) * 4];
    cwS[tid][0] = w.x; cwS[tid][1] = w.y; cwS[tid][2] = w.z; cwS[tid][3] = w.w;
  }
  __syncthreads();

  for (int i = tid; i < 4096; i += 256) {
    const int d = i >> 6, l = i & 63;
    float a = cbS[d] + cwS[d][0] * xin[d][l] + cwS[d][1] * xin[d][l + 1] +
              cwS[d][2] * xin[d][l + 2] + cwS[d][3] * xin[d][l + 3];
    To[d][l] = a / (1.f + __expf(-a));
  }
  __syncthreads();

  for (int i = tid; i < 4096; i += 256) {
    const int l = i >> 6, dd = i & 63;
    float v = To[dd][l];  // stride-65: conflict-free
    ushort h = f2h(v);
    xcT_hi[(size_t)(l0 + l) * DIN + d0 + dd] = h;
    xcT_lo[(size_t)(l0 + l) * DIN + d0 + dd] = f2h((v - h2f(h)) * 2048.f);
  }
  __syncthreads();  // To fully consumed; reuse for z tile

  for (int i = tid; i < 1024; i += 256) {
    const int d = i >> 4, q = i & 15;
    float4 v = *(const float4*)&xz[(size_t)(DIN + d0 + d) * SEQ + l0 + q * 4];
    To[d][q * 4 + 0] = v.x / (1.f + __expf(-v.x));
    To[d][q * 4 + 1] = v.y / (1.f + __expf(-v.y));
    To[d][q * 4 + 2] = v.z / (1.f + __expf(-v.z));
    To[d][q * 4 + 3] = v.w / (1.f + __expf(-v.w));
  }
  __syncthreads();
  for (int i = tid; i < 4096; i += 256) {
    const int l = i >> 6, dd = i & 63;
    zs[(size_t)(l0 + l) * DIN + d0 + dd] = split2(To[dd][l]);
  }
}

// Reduce 16 x_proj split-K slabs (SEQ x 192, l-major) -> B/C tables +
// dt rows as (l,r) f16 hi/lo planes.
__global__ __launch_bounds__(256) void reduce_dblT_kernel(const float* __restrict__ p,
                                                          float* __restrict__ BT1,
                                                          float* __restrict__ CT1,
                                                          float* __restrict__ BT2,
                                                          float* __restrict__ CT2,
                                                          ushort* __restrict__ dtT_hi,
                                                          ushort* __restrict__ dtT_lo) {
  const int NE = SEQ * 192;
  const int idx = blockIdx.x * 256 + threadIdx.x;
  float s = 0.f;
#pragma unroll
  for (int cc = 0; cc < 16; ++cc) s += p[(size_t)cc * NE + idx];
  const int l = idx / 192, k = idx - l * 192;
  if (k < 64) {
    const size_t off = (size_t)l * 64 + k;
    const ushort hh = f2h(s);
    dtT_hi[off] = hh; dtT_lo[off] = f2h((s - h2f(hh)) * 2048.f);
  } else if (k < 80)  BT1[l * NST + (k - 64)] = s;
  else if (k < 96)    CT1[l * NST + (k - 80)] = s;
  else if (k < 160) {
    const size_t off = 131072 + (size_t)l * 64 + (k - 96);
    const ushort hh = f2h(s);
    dtT_hi[off] = hh; dtT_lo[off] = f2h((s - h2f(hh)) * 2048.f);
  }
  else if (k < 176)   BT2[l * NST + (k - 160)] = s;
  else                CT2[l * NST + (k - 176)] = s;
}

// =====================================================================
// Chunked selective scan, BOTH branches fused per thread (u/sp read once).
// sp as interleaved ushort2; u as separate hi/lo planes (GEMM needs them).
// =====================================================================
__global__ __launch_bounds__(256) void scan_phase_a(const ushort* __restrict__ uhi,
                                                    const ushort* __restrict__ ulo,
                                                    const ushort2* __restrict__ sp1,
                                                    const ushort2* __restrict__ sp2,
                                                    const float* __restrict__ BT1,
                                                    const float* __restrict__ BT2,
                                                    const float* __restrict__ Al1,
                                                    const float* __restrict__ Al2,
                                                    float* __restrict__ hend,
                                                    float* __restrict__ Pend) {
  const int c = blockIdx.y, t0 = c * CH;
  const int d = blockIdx.x * 256 + threadIdx.x;
  const size_t gbase = (size_t)t0 * DIN + d;

  __shared__ __align__(16) float Bs[2][CH][NST];
  {
    const int j = threadIdx.x;  // 2*CH*NST floats = 256 float4
    if (j < 128) ((float4*)&Bs[0][0][0])[j] = ((const float4*)&BT1[(size_t)t0 * NST])[j];
    else ((float4*)&Bs[1][0][0])[j - 128] = ((const float4*)&BT2[(size_t)t0 * NST])[j - 128];
  }
  __syncthreads();

  bool fast = true;
#pragma unroll
  for (int n = 0; n < NST; ++n) {
    float k1 = __expf(Al1[(size_t)d * NST + n]);
    float k2 = __expf(Al2[(size_t)d * NST + n]);
    fast = fast && (fabsf(k1 - (float)(n + 1)) < 1e-3f) && (fabsf(k2 - (float)(n + 1)) < 1e-3f);
  }
  float h1[NST], h2[NST];
#pragma unroll
  for (int n = 0; n < NST; ++n) { h1[n] = 0.f; h2[n] = 0.f; }
  float S1 = 0.f, S2 = 0.f;

  if (fast) {
    for (int tt = 0; tt < CH / 4; ++tt) {
      float s1[4], s2[4], ua[4];
#pragma unroll
      for (int j = 0; j < 4; ++j) {
        const size_t idx = gbase + (size_t)(tt * 4 + j) * DIN;
        s1[j] = join2(sp1[idx]);
        s2[j] = join2(sp2[idx]);
        ua[j] = h2f(uhi[idx]) + h2f(ulo[idx]) * (1.f / 2048.f);
      }
#pragma unroll
      for (int j = 0; j < 4; ++j) {
        const int t = tt * 4 + j;
        S1 += s1[j]; S2 += s2[j];
        const float spu1 = s1[j] * ua[j], spu2 = s2[j] * ua[j];
        float p[NST];
        powers16(__expf(-s1[j]), p);
#pragma unroll
        for (int n = 0; n < NST; ++n) h1[n] = fmaf(p[n], h1[n], spu1 * Bs[0][t][n]);
        powers16(__expf(-s2[j]), p);
#pragma unroll
        for (int n = 0; n < NST; ++n) h2[n] = fmaf(p[n], h2[n], spu2 * Bs[1][t][n]);
      }
    }
  } else {
    float A1e[NST], A2e[NST];
#pragma unroll
    for (int n = 0; n < NST; ++n) {
      A1e[n] = -__expf(Al1[(size_t)d * NST + n]) * LOG2E;
      A2e[n] = -__expf(Al2[(size_t)d * NST + n]) * LOG2E;
    }
    for (int tt = 0; tt < CH / 4; ++tt) {
      float s1[4], s2[4], ua[4];
#pragma unroll
      for (int j = 0; j < 4; ++j) {
        const size_t idx = gbase + (size_t)(tt * 4 + j) * DIN;
        s1[j] = join2(sp1[idx]);
        s2[j] = join2(sp2[idx]);
        ua[j] = h2f(uhi[idx]) + h2f(ulo[idx]) * (1.f / 2048.f);
      }
#pragma unroll
      for (int j = 0; j < 4; ++j) {
        const int t = tt * 4 + j;
        S1 += s1[j]; S2 += s2[j];
        const float spu1 = s1[j] * ua[j], spu2 = s2[j] * ua[j];
#pragma unroll
        for (int n = 0; n < NST; ++n) {
          h1[n] = fmaf(exp2f(A1e[n] * s1[j]), h1[n], spu1 * Bs[0][t][n]);
          h2[n] = fmaf(exp2f(A2e[n] * s2[j]), h2[n], spu2 * Bs[1][t][n]);
        }
      }
    }
  }

  float P1[NST], P2[NST];
  if (fast) {
    powers16(__expf(-S1), P1);
    powers16(__expf(-S2), P2);
  } else {
#pragma unroll
    for (int n = 0; n < NST; ++n) {
      P1[n] = exp2f(-__expf(Al1[(size_t)d * NST + n]) * LOG2E * S1);
      P2[n] = exp2f(-__expf(Al2[(size_t)d * NST + n]) * LOG2E * S2);
    }
  }
  const size_t b1 = ((size_t)c * DIN + d) * NST;
  const size_t b2 = ((size_t)(NCH + c) * DIN + d) * NST;
#pragma unroll
  for (int n = 0; n < NST; n += 4) {
    *(float4*)&hend[b1 + n] = make_float4(h1[n], h1[n + 1], h1[n + 2], h1[n + 3]);
    *(float4*)&Pend[b1 + n] = make_float4(P1[n], P1[n + 1], P1[n + 2], P1[n + 3]);
    *(float4*)&hend[b2 + n] = make_float4(h2[n], h2[n + 1], h2[n + 2], h2[n + 3]);
    *(float4*)&Pend[b2 + n] = make_float4(P2[n], P2[n + 1], P2[n + 2], P2[n + 3]);
  }
}

// Merged: blocks [0,256) do the chunk-carry (hin overwrites Pend in place);
// blocks [256,2304) convert outw -> f16 hi plane.
__global__ __launch_bounds__(256) void carry_cvt(const float* __restrict__ hend,
                                                 float* __restrict__ PendHin,
                                                 const float* __restrict__ outw,
                                                 ushort* __restrict__ ow_hi) {
  const int b = blockIdx.x;
  if (b < 256) {
    const int flat = b * 256 + threadIdx.x;
    const int br = flat >> 15;
    const int dn = flat & 32767;
    float h = 0.f;
    for (int c = 0; c < NCH; ++c) {
      size_t idx = ((size_t)(br * NCH + c) << 15) + dn;
      float Pv = PendHin[idx];
      float he = hend[idx];
      PendHin[idx] = h;
      h = fmaf(Pv, h, he);
    }
  } else {
    const size_t i = ((size_t)(b - 256) * 256 + threadIdx.x) * 4;  // < 2,097,152
    float4 v = *(const float4*)&outw[i];
    *(ushort4*)&ow_hi[i] = make_ushort4(f2h(v.x), f2h(v.y), f2h(v.z), f2h(v.w));
  }
}

// Phase C fused: both branches per thread; emits yd = (y1-y2+(D1-D2)u)*silu(z)
// directly as f16 hi/lo planes IN PLACE over the u planes.
__global__ __launch_bounds__(256) void scan_phase_c(const ushort* __restrict__ uhi,
                                                    const ushort* __restrict__ ulo,
                                                    const ushort2* __restrict__ sp1,
                                                    const ushort2* __restrict__ sp2,
                                                    const float* __restrict__ BT1,
                                                    const float* __restrict__ CT1,
                                                    const float* __restrict__ BT2,
                                                    const float* __restrict__ CT2,
                                                    const float* __restrict__ Al1,
                                                    const float* __restrict__ Al2,
                                                    const float* __restrict__ D1,
                                                    const float* __restrict__ D2,
                                                    const float* __restrict__ hin,
                                                    const ushort2* __restrict__ zs,
                                                    ushort* __restrict__ yd_hi,
                                                    ushort* __restrict__ yd_lo) {
  const int c = blockIdx.y, t0 = c * CH;
  const int d = blockIdx.x * 256 + threadIdx.x;
  const size_t gbase = (size_t)t0 * DIN + d;

  __shared__ __align__(16) float Bs[2][CH][NST];
  __shared__ __align__(16) float Cs[2][CH][NST];
  {
    const int j = threadIdx.x;
    if (j < 128) {
      ((float4*)&Bs[0][0][0])[j] = ((const float4*)&BT1[(size_t)t0 * NST])[j];
      ((float4*)&Cs[0][0][0])[j] = ((const float4*)&CT1[(size_t)t0 * NST])[j];
    } else {
      ((float4*)&Bs[1][0][0])[j - 128] = ((const float4*)&BT2[(size_t)t0 * NST])[j - 128];
      ((float4*)&Cs[1][0][0])[j - 128] = ((const float4*)&CT2[(size_t)t0 * NST])[j - 128];
    }
  }
  __syncthreads();

  bool fast = true;
#pragma unroll
  for (int n = 0; n < NST; ++n) {
    float k1 = __expf(Al1[(size_t)d * NST + n]);
    float k2 = __expf(Al2[(size_t)d * NST + n]);
    fast = fast && (fabsf(k1 - (float)(n + 1)) < 1e-3f) && (fabsf(k2 - (float)(n + 1)) < 1e-3f);
  }
  const float Ddd = D1[d] - D2[d];
  float h1[NST], h2[NST];
  const size_t hb1 = ((size_t)c * DIN + d) * NST;
  const size_t hb2 = ((size_t)(NCH + c) * DIN + d) * NST;
#pragma unroll
  for (int n = 0; n < NST; n += 4) {
    float4 v1 = *(const float4*)&hin[hb1 + n];
    h1[n] = v1.x; h1[n + 1] = v1.y; h1[n + 2] = v1.z; h1[n + 3] = v1.w;
    float4 v2 = *(const float4*)&hin[hb2 + n];
    h2[n] = v2.x; h2[n + 1] = v2.y; h2[n + 2] = v2.z; h2[n + 3] = v2.w;
  }

  if (fast) {
    for (int tt = 0; tt < CH / 4; ++tt) {
      float s1[4], s2[4], ua[4];
#pragma unroll
      for (int j = 0; j < 4; ++j) {
        const size_t idx = gbase + (size_t)(tt * 4 + j) * DIN;
        s1[j] = join2(sp1[idx]);
        s2[j] = join2(sp2[idx]);
        ua[j] = h2f(uhi[idx]) + h2f(ulo[idx]) * (1.f / 2048.f);
      }
#pragma unroll
      for (int j = 0; j < 4; ++j) {
        const int t = tt * 4 + j;
        const size_t idx = gbase + (size_t)t * DIN;
        const float spu1 = s1[j] * ua[j], spu2 = s2[j] * ua[j];
        float p[NST];
        float y1 = 0.f, y2 = 0.f;
        powers16(__expf(-s1[j]), p);
#pragma unroll
        for (int n = 0; n < NST; ++n) {
          h1[n] = fmaf(p[n], h1[n], spu1 * Bs[0][t][n]);
          y1 = fmaf(h1[n], Cs[0][t][n], y1);
        }
        powers16(__expf(-s2[j]), p);
#pragma unroll
        for (int n = 0; n < NST; ++n) {
          h2[n] = fmaf(p[n], h2[n], spu2 * Bs[1][t][n]);
          y2 = fmaf(h2[n], Cs[1][t][n], y2);
        }
        const float zv = join2(zs[idx]);
        const float yd = (y1 - y2 + Ddd * ua[j]) * zv;
        const ushort hh = f2h(yd);
        yd_hi[idx] = hh;
        yd_lo[idx] = f2h((yd - h2f(hh)) * 2048.f);
      }
    }
  } else {
    float A1e[NST], A2e[NST];
#pragma unroll
    for (int n = 0; n < NST; ++n) {
      A1e[n] = -__expf(Al1[(size_t)d * NST + n]) * LOG2E;
      A2e[n] = -__expf(Al2[(size_t)d * NST + n]) * LOG2E;
    }
    for (int tt = 0; tt < CH / 4; ++tt) {
      float s1[4], s2[4], ua[4];
#pragma unroll
      for (int j = 0; j < 4; ++j) {
        const size_t idx = gbase + (size_t)(tt * 4 + j) * DIN;
        s1[j] = join2(sp1[idx]);
        s2[j] = join2(sp2[idx]);
        ua[j] = h2f(uhi[idx]) + h2f(ulo[idx]) * (1.f / 2048.f);
      }
#pragma unroll
      for (int j = 0; j < 4; ++j) {
        const int t = tt * 4 + j;
        const size_t idx = gbase + (size_t)t * DIN;
        const float spu1 = s1[j] * ua[j], spu2 = s2[j] * ua[j];
        float y1 = 0.f, y2 = 0.f;
#pragma unroll
        for (int n = 0; n < NST; ++n) {
          h1[n] = fmaf(exp2f(A1e[n] * s1[j]), h1[n], spu1 * Bs[0][t][n]);
          y1 = fmaf(h1[n], Cs[0][t][n], y1);
          h2[n] = fmaf(exp2f(A2e[n] * s2[j]), h2[n], spu2 * Bs[1][t][n]);
          y2 = fmaf(h2[n], Cs[1][t][n], y2);
        }
        const float zv = join2(zs[idx]);
        const float yd = (y1 - y2 + Ddd * ua[j]) * zv;
        const ushort hh = f2h(yd);
        yd_hi[idx] = hh;
        yd_lo[idx] = f2h((yd - h2f(hh)) * 2048.f);
      }
    }
  }
}

// =====================================================================
extern "C" void kernel_launch(void* const* d_in, const int* in_sizes, int n_in,
                              void* d_out, int out_size, void* d_ws, size_t ws_size,
                              hipStream_t stream) {
  const float* hidden = (const float*)d_in[0];
  const float* in_proj_w = (const float*)d_in[1];
  const float* conv_w = (const float*)d_in[2];
  const float* conv_b = (const float*)d_in[3];
  const float* x1w = (const float*)d_in[4];
  const float* dtw1 = (const float*)d_in[5];
  const float* dtb1 = (const float*)d_in[6];
  const float* Al1 = (const float*)d_in[7];
  const float* D1 = (const float*)d_in[8];
  const float* x2w = (const float*)d_in[9];
  const float* dtw2 = (const float*)d_in[10];
  const float* dtb2 = (const float*)d_in[11];
  const float* Al2 = (const float*)d_in[12];
  const float* D2 = (const float*)d_in[13];
  const float* outw = (const float*)d_in[14];
  float* out = (float*)d_out;

  // Workspace layout (floats), same 34.47M footprint.
  float* ws = (float*)d_ws;
  float* xz = ws;                                    // 8.39M  (x rows, z rows)
  float* xcTbuf = xz + (size_t)4096 * SEQ;           // 4.19M  u f16 hi/lo planes
  float* dtTbuf = xcTbuf + (size_t)SEQ * DIN;        // 393K   dtT f16 hi/lo planes
  float* spbuf1 = dtTbuf + (size_t)192 * SEQ;        // 4.19M  sp1 ushort2 plane
  float* spbuf2 = spbuf1 + (size_t)SEQ * DIN;        // 4.19M  sp2 ushort2 plane
  float* zsbuf = spbuf2 + (size_t)SEQ * DIN;         // 4.19M  silu(z) ushort2 plane
  float* hendB = zsbuf + (size_t)SEQ * DIN;          // 4.19M
  float* PendB = hendB + (size_t)2 * NCH * DIN * NST;// 4.19M
  float* BT1 = PendB + (size_t)2 * NCH * DIN * NST;  // 32K each
  float* CT1 = BT1 + (size_t)SEQ * NST;
  float* BT2 = CT1 + (size_t)SEQ * NST;
  float* CT2 = BT2 + (size_t)SEQ * NST;
  float* wxp = CT2 + (size_t)SEQ * NST;              // 393K stacked x_proj W planes

  // Aliases (lifetime-disjoint):
  ushort* xcT_hi = (ushort*)xcTbuf;                  // u planes, steps 3..scan C
  ushort* xcT_lo = (ushort*)(xcTbuf + 2097152);
  ushort* dtT_hi = (ushort*)dtTbuf;                  // dt rows (l,64) x 2 branches
  ushort* dtT_lo = dtT_hi + 262144;
  ushort2* sp1 = (ushort2*)spbuf1;                   // interleaved sp planes
  ushort2* sp2 = (ushort2*)spbuf2;
  ushort2* zs = (ushort2*)zsbuf;                     // interleaved silu(z) plane
  ushort* w_hi = (ushort*)zsbuf;                     // in_proj_w planes (dead after step 2,
  ushort* w_lo = (ushort*)(zsbuf + 2097152);         //   before conv writes zs plane)
  ushort* h_hi = (ushort*)hendB;                     // hidden hi plane (dead after step 2)
  ushort* dw_hi = ((ushort*)hendB) + 2097152;        // dtw planes behind h_hi (dead
  ushort* dw_lo = dw_hi + 262144;                    //   before scan_a writes hendB)
  ushort* wx_hi = (ushort*)wxp;                      // stacked x_proj weights 192x2048
  ushort* wx_lo = (ushort*)(wxp + 196608);
  float* xp_part = spbuf1;                           // 16 slabs x SEQ*192*4B = 25.2MB,
                                                     //   spans spbuf1+spbuf2 (sp written later)
  ushort* yd_hi = (ushort*)xcTbuf;                   // yd planes overwrite u in-place
  ushort* yd_lo = (ushort*)(xcTbuf + 2097152);
  ushort* ow_hi = (ushort*)xz;                       // outw hi plane in dead xz
  float* opart = spbuf1;                             // out_proj partials: 33.6MB spans
                                                     //   spbuf1+spbuf2 (sp dead by then)
  dim3 blk(256);

  // 1) fused split-convert: in_proj_w, hidden (hi only), x1w, x2w, dtw1, dtw2
  cvt_fused<<<dim3(6784), blk, 0, stream>>>(in_proj_w, hidden, x1w, x2w, dtw1, dtw2,
                                            w_hi, w_lo, h_hi, wx_hi, wx_lo, dw_hi, dw_lo);

  // 2) in_proj via f16 MFMA 2-pass (dual-32 stages) -> xz (e,l)
  gemm3p<128, 128, 1, 2><<<dim3(SEQ / 128, 4096 / 128, 1), blk, 0, stream>>>(
      w_hi, w_lo, h_hi, h_hi, xz, 4096, SEQ, DMODEL);

  // 3) conv + silu -> u f16 planes (l,d); silu(z) -> ushort2 plane (l,d)
  conv_tr_kernel<<<dim3(SEQ / 64, DIN / 64), blk, 0, stream>>>(
      xz, conv_w, conv_b, xcT_hi, xcT_lo, zs);

  // 4) x_proj swapped: C[l, k(192)] = sum_d xcT[l,d]*wx[k,d], split-K=16
  gemm3p<128, 64, 16, 0><<<dim3(192 / 64, SEQ / 128, 16), blk, 0, stream>>>(
      xcT_hi, xcT_lo, wx_hi, wx_lo, xp_part, SEQ, 192, DIN);

  // 5) reduce 16 slabs -> B/C tables + dtT f16 planes
  reduce_dblT_kernel<<<dim3(192 * SEQ / 256), blk, 0, stream>>>(
      xp_part, BT1, CT1, BT2, CT2, dtT_hi, dtT_lo);

  // 6) dt projection on MFMA (swapped operands, 16B-store epilogue)
  dt_mfma<<<dim3(SEQ / 128, DIN / 128, 2), blk, 0, stream>>>(
      dtT_hi, dtT_lo, dw_hi, dw_lo, dtb1, dtb2, sp1, sp2);

  // 7) chunked scan (A, carry+cvt, C)
  scan_phase_a<<<dim3(DIN / 256, NCH), blk, 0, stream>>>(
      xcT_hi, xcT_lo, sp1, sp2, BT1, BT2, Al1, Al2, hendB, PendB);
  carry_cvt<<<dim3(2304), blk, 0, stream>>>(hendB, PendB, outw, ow_hi);
  scan_phase_c<<<dim3(DIN / 256, NCH), blk, 0, stream>>>(
      xcT_hi, xcT_lo, sp1, sp2, BT1, CT1, BT2, CT2, Al1, Al2,
      D1, D2, PendB, zs, yd_hi, yd_lo);

  // 8) out_proj via f16 MFMA 2-pass (dual-32 stages), split-K=4
  gemm3p<128, 128, 4, 2><<<dim3(DMODEL / 128, SEQ / 128, 4), blk, 0, stream>>>(
      yd_hi, yd_lo, ow_hi, ow_hi, opart, SEQ, DMODEL, DIN);
  reduce_out<<<dim3(SEQ * DMODEL / 1024), blk, 0, stream>>>(opart, out, SEQ * DMODEL);
}

// Round 12
// 291.030 us; speedup vs baseline: 1.3595x; 1.0533x over previous
//
#include <hip/hip_runtime.h>
#include <math.h>

#define SEQ 2048
#define DMODEL 1024
#define DIN 2048
#define NST 16
#define DTR 64
#define CH 32
#define NCH (SEQ / CH)
#define LOG2E 1.4426950408889634f

typedef __attribute__((ext_vector_type(8))) _Float16 f16x8;
typedef __attribute__((ext_vector_type(4))) float f32x4;

// f16 split (11-bit mantissa): hi = f16(v), lo = f16((v-hi)*2048).
// hi + lo*2^-11 reconstructs to ~2^-22 relative: NOT a precision cut.
__device__ __forceinline__ ushort f2h(float f) {
  union { _Float16 h; ushort u; } c; c.h = (_Float16)f; return c.u;
}
__device__ __forceinline__ float h2f(ushort u) {
  union { ushort u; _Float16 h; } c; c.u = u; return (float)c.h;
}
__device__ __forceinline__ ushort2 split2(float v) {
  ushort hh = f2h(v);
  return make_ushort2(hh, f2h((v - h2f(hh)) * 2048.f));
}
__device__ __forceinline__ float join2(ushort2 p) {
  return h2f(p.x) + h2f(p.y) * (1.f / 2048.f);
}
// Fast softplus: max(v,0) + log(1+exp(-|v|)) on HW v_log/v_exp.
__device__ __forceinline__ float splus(float v) {
  return fmaxf(v, 0.f) + __logf(1.f + __expf(-fabsf(v)));
}
// p[n] = e^(n+1), depth-4 mul tree (no transcendentals).
__device__ __forceinline__ void powers16(float e, float* p) {
  float e2 = e * e, e4 = e2 * e2, e8 = e4 * e4;
  p[0] = e;       p[1] = e2;       p[2] = e2 * e;   p[3] = e4;
  p[4] = e4 * e;  p[5] = e4 * e2;  p[6] = e4 * p[2]; p[7] = e8;
  p[8] = e8 * e;  p[9] = e8 * e2;  p[10] = e8 * p[2]; p[11] = e8 * e4;
  p[12] = e8 * p[4]; p[13] = e8 * p[5]; p[14] = e8 * p[6]; p[15] = e8 * e8;
}

#define GLL(g, l) __builtin_amdgcn_global_load_lds( \
    (const __attribute__((address_space(1))) void*)(g), \
    (__attribute__((address_space(3))) void*)(l), 16, 0, 0)

// Bijective XCD swizzle over the (x,y) grid; requires nwg_xy % 8 == 0.
#define XCD_SWZ(BMv, BNv)                                              \
  const int nwg_ = gridDim.x * gridDim.y;                              \
  const int flat_ = blockIdx.y * gridDim.x + blockIdx.x;               \
  const int swz_ = (flat_ & 7) * (nwg_ >> 3) + (flat_ >> 3);           \
  const int m0 = (swz_ / gridDim.x) * (BMv);                           \
  const int n0 = (swz_ % gridDim.x) * (BNv);

// =====================================================================
// Split-f16 MFMA GEMM (round-6 proven dual-32-stage version).
// MODE 0: 3-pass; MODE 2: 2-pass (B_lo dropped).
// C = acc + accL * 2^-11 (lo planes stored pre-scaled x2048).
// =====================================================================
template<int BM, int BN, int SPLITK, int MODE>
__global__ __launch_bounds__(256, 2) void gemm3p(const ushort* __restrict__ Ahi,
                                                 const ushort* __restrict__ Alo,
                                                 const ushort* __restrict__ Bhi,
                                                 const ushort* __restrict__ Blo,
                                                 float* __restrict__ C,
                                                 int M, int N, int K) {
  constexpr int WM = BM / 2, WN = BN / 2, TM = WM / 16, TN = WN / 16;
  constexpr int SA = BM / 16, SB = BN / 16;
  constexpr bool dropB = (MODE == 2);
  __shared__ __align__(16) ushort sAh[2][BM * 32], sAl[2][BM * 32];
  __shared__ __align__(16) ushort sBh[2][BN * 32];
  __shared__ __align__(16) ushort sBl[2][dropB ? 16 : BN * 32];
  const int tid = threadIdx.x, wid = tid >> 6, lane = tid & 63;
  XCD_SWZ(BM, BN)
  const int Kc = K / SPLITK, kbeg = blockIdx.z * Kc;
  const int wm0 = (wid >> 1) * WM, wn0 = (wid & 1) * WN;
  const int fr = lane & 15;
  const int lrow = lane >> 2;
  const int lkc = (lane & 3) ^ ((lane >> 3) & 3);
  const int fpo = fr * 32 + (((lane >> 4) ^ ((lane >> 1) & 3)) * 8);

  f32x4 acc[TM][TN], accL[TM][TN];
#pragma unroll
  for (int mi = 0; mi < TM; ++mi)
#pragma unroll
    for (int ni = 0; ni < TN; ++ni)
#pragma unroll
      for (int r = 0; r < 4; ++r) { acc[mi][ni][r] = 0.f; accL[mi][ni][r] = 0.f; }

  for (int k0 = 0; k0 < Kc; k0 += 64) {
    __syncthreads();
#pragma unroll
    for (int kk = 0; kk < 2; ++kk) {
      const int kg = kbeg + k0 + kk * 32 + lkc * 8;
#pragma unroll
      for (int i = 0; i < SA / 4; ++i) {
        const int seg = wid * (SA / 4) + i;
        const size_t ga = (size_t)(m0 + seg * 16 + lrow) * K + kg;
        GLL(&Ahi[ga], &sAh[kk][seg * 512]);
        GLL(&Alo[ga], &sAl[kk][seg * 512]);
      }
#pragma unroll
      for (int i = 0; i < SB / 4; ++i) {
        const int seg = wid * (SB / 4) + i;
        const size_t ga = (size_t)(n0 + seg * 16 + lrow) * K + kg;
        GLL(&Bhi[ga], &sBh[kk][seg * 512]);
        if constexpr (!dropB) GLL(&Blo[ga], &sBl[kk][seg * 512]);
      }
    }
    __syncthreads();

#pragma unroll
    for (int kk = 0; kk < 2; ++kk) {
      f16x8 ah[TM], al[TM], bh[TN], bl[TN];
#pragma unroll
      for (int mi = 0; mi < TM; ++mi) {
        const int r = (wm0 / 16 + mi) * 512 + fpo;
        ah[mi] = *(const f16x8*)&sAh[kk][r];
        al[mi] = *(const f16x8*)&sAl[kk][r];
      }
#pragma unroll
      for (int ni = 0; ni < TN; ++ni) {
        const int r = (wn0 / 16 + ni) * 512 + fpo;
        bh[ni] = *(const f16x8*)&sBh[kk][r];
        if constexpr (!dropB) bl[ni] = *(const f16x8*)&sBl[kk][r];
      }
#pragma unroll
      for (int mi = 0; mi < TM; ++mi)
#pragma unroll
        for (int ni = 0; ni < TN; ++ni) {
          acc[mi][ni] = __builtin_amdgcn_mfma_f32_16x16x32_f16(ah[mi], bh[ni], acc[mi][ni], 0, 0, 0);
          accL[mi][ni] = __builtin_amdgcn_mfma_f32_16x16x32_f16(al[mi], bh[ni], accL[mi][ni], 0, 0, 0);
          if constexpr (!dropB)
            accL[mi][ni] = __builtin_amdgcn_mfma_f32_16x16x32_f16(ah[mi], bl[ni], accL[mi][ni], 0, 0, 0);
        }
    }
  }

  float* __restrict__ Co = C + (size_t)blockIdx.z * M * N;
#pragma unroll
  for (int mi = 0; mi < TM; ++mi)
#pragma unroll
    for (int ni = 0; ni < TN; ++ni)
#pragma unroll
      for (int r = 0; r < 4; ++r)
        Co[(size_t)(m0 + wm0 + mi * 16 + (lane >> 4) * 4 + r) * N + n0 + wn0 + ni * 16 + fr] =
            acc[mi][ni][r] + accL[mi][ni][r] * (1.f / 2048.f);
}

// =====================================================================
// dt projection on MFMA, SWAPPED operands: C[d][l] = sum_k dtw[d,k]*dtT[l,k]
// -> epilogue packs 4 consecutive d into ONE 16B store at sp[l*DIN+d].
// =====================================================================
__global__ __launch_bounds__(256, 2) void dt_mfma(const ushort* __restrict__ dtT_hi,
                                                  const ushort* __restrict__ dtT_lo,
                                                  const ushort* __restrict__ dw_hi,
                                                  const ushort* __restrict__ dw_lo,
                                                  const float* __restrict__ b1,
                                                  const float* __restrict__ b2,
                                                  ushort2* __restrict__ sp1,
                                                  ushort2* __restrict__ sp2) {
  const int br = blockIdx.z;
  const ushort* __restrict__ Ah = dw_hi + (size_t)br * 131072;   // A = dtw (d rows)
  const ushort* __restrict__ Al_ = dw_lo + (size_t)br * 131072;
  const ushort* __restrict__ Bh = dtT_hi + (size_t)br * 131072;  // B = dtT (l rows)
  const ushort* __restrict__ Bl = dtT_lo + (size_t)br * 131072;
  const float* __restrict__ bias = br ? b2 : b1;
  ushort2* __restrict__ o = br ? sp2 : sp1;
  __shared__ __align__(16) ushort sAh[2][4096], sAl[2][4096];
  __shared__ __align__(16) ushort sBh[2][4096], sBl[2][4096];
  const int tid = threadIdx.x, wid = tid >> 6, lane = tid & 63;
  XCD_SWZ(128, 128)   // m0 -> d tile, n0 -> l tile
  const int wm0 = (wid >> 1) * 64, wn0 = (wid & 1) * 64;
  const int fr = lane & 15;
  const int lrow = lane >> 2;
  const int lkc = (lane & 3) ^ ((lane >> 3) & 3);
  const int fpo = fr * 32 + (((lane >> 4) ^ ((lane >> 1) & 3)) * 8);

  f32x4 acc[4][4], accL[4][4];
#pragma unroll
  for (int mi = 0; mi < 4; ++mi)
#pragma unroll
    for (int ni = 0; ni < 4; ++ni)
#pragma unroll
      for (int r = 0; r < 4; ++r) { acc[mi][ni][r] = 0.f; accL[mi][ni][r] = 0.f; }

#pragma unroll
  for (int kk = 0; kk < 2; ++kk) {
    const int kg = kk * 32 + lkc * 8;
#pragma unroll
    for (int i = 0; i < 2; ++i) {
      const int seg = wid * 2 + i;
      const size_t ga = (size_t)(m0 + seg * 16 + lrow) * 64 + kg;
      GLL(&Ah[ga], &sAh[kk][seg * 512]);
      GLL(&Al_[ga], &sAl[kk][seg * 512]);
      const size_t gb = (size_t)(n0 + seg * 16 + lrow) * 64 + kg;
      GLL(&Bh[gb], &sBh[kk][seg * 512]);
      GLL(&Bl[gb], &sBl[kk][seg * 512]);
    }
  }
  __syncthreads();

#pragma unroll
  for (int kk = 0; kk < 2; ++kk) {
    f16x8 ah[4], al[4], bh[4], bl[4];
#pragma unroll
    for (int mi = 0; mi < 4; ++mi) {
      const int r = (wm0 / 16 + mi) * 512 + fpo;
      ah[mi] = *(const f16x8*)&sAh[kk][r];
      al[mi] = *(const f16x8*)&sAl[kk][r];
    }
#pragma unroll
    for (int ni = 0; ni < 4; ++ni) {
      const int r = (wn0 / 16 + ni) * 512 + fpo;
      bh[ni] = *(const f16x8*)&sBh[kk][r];
      bl[ni] = *(const f16x8*)&sBl[kk][r];
    }
#pragma unroll
    for (int mi = 0; mi < 4; ++mi)
#pragma unroll
      for (int ni = 0; ni < 4; ++ni) {
        acc[mi][ni] = __builtin_amdgcn_mfma_f32_16x16x32_f16(ah[mi], bh[ni], acc[mi][ni], 0, 0, 0);
        accL[mi][ni] = __builtin_amdgcn_mfma_f32_16x16x32_f16(al[mi], bh[ni], accL[mi][ni], 0, 0, 0);
        accL[mi][ni] = __builtin_amdgcn_mfma_f32_16x16x32_f16(ah[mi], bl[ni], accL[mi][ni], 0, 0, 0);
      }
  }

  // Epilogue: 16B stores (4 consecutive d per fragment).
#pragma unroll
  for (int mi = 0; mi < 4; ++mi) {
    const int dbase = m0 + wm0 + mi * 16 + (lane >> 4) * 4;
    const float4 b4 = *(const float4*)&bias[dbase];
    const float bv[4] = {b4.x, b4.y, b4.z, b4.w};
#pragma unroll
    for (int ni = 0; ni < 4; ++ni) {
      const int l = n0 + wn0 + ni * 16 + fr;
      uint pk[4];
#pragma unroll
      for (int r = 0; r < 4; ++r) {
        const ushort2 s = split2(splus(acc[mi][ni][r] + accL[mi][ni][r] * (1.f / 2048.f) + bv[r]));
        pk[r] = (uint)s.x | ((uint)s.y << 16);
      }
      *(uint4*)&o[(size_t)l * DIN + dbase] = make_uint4(pk[0], pk[1], pk[2], pk[3]);
    }
  }
}

__device__ __forceinline__ void split_store4h(float4 v, ushort* hi, ushort* lo, size_t i) {
  ushort h0 = f2h(v.x), h1 = f2h(v.y), h2 = f2h(v.z), h3 = f2h(v.w);
  *(ushort4*)&hi[i] = make_ushort4(h0, h1, h2, h3);
  *(ushort4*)&lo[i] = make_ushort4(f2h((v.x - h2f(h0)) * 2048.f), f2h((v.y - h2f(h1)) * 2048.f),
                                   f2h((v.z - h2f(h2)) * 2048.f), f2h((v.w - h2f(h3)) * 2048.f));
}

// One launch converting in_proj_w, hidden, x1w, x2w, dtw1, dtw2 -> f16 planes.
__global__ __launch_bounds__(256) void cvt_fused(const float* __restrict__ inw,
                                                 const float* __restrict__ hid,
                                                 const float* __restrict__ x1w,
                                                 const float* __restrict__ x2w,
                                                 const float* __restrict__ dtw1,
                                                 const float* __restrict__ dtw2,
                                                 ushort* __restrict__ w_hi, ushort* __restrict__ w_lo,
                                                 ushort* __restrict__ h_hi,
                                                 ushort* __restrict__ wx_hi, ushort* __restrict__ wx_lo,
                                                 ushort* __restrict__ dw_hi, ushort* __restrict__ dw_lo) {
  const int q = blockIdx.x * 256 + threadIdx.x;  // float4 index
  if (q >= 1048576 && q < 1572864) {
    const size_t i = (size_t)(q - 1048576) * 4;
    float4 v = *(const float4*)&hid[i];
    *(ushort4*)&h_hi[i] = make_ushort4(f2h(v.x), f2h(v.y), f2h(v.z), f2h(v.w));
    return;
  }
  const float* src; ushort* dhi; ushort* dlo; int base;
  if (q < 1048576)       { src = inw; dhi = w_hi;  dlo = w_lo;  base = q; }
  else if (q < 1622016)  { src = x1w; dhi = wx_hi; dlo = wx_lo; base = q - 1572864; }
  else if (q < 1671168)  { src = x2w; dhi = wx_hi + 196608; dlo = wx_lo + 196608; base = q - 1622016; }
  else if (q < 1703936)  { src = dtw1; dhi = dw_hi; dlo = dw_lo; base = q - 1671168; }
  else                   { src = dtw2; dhi = dw_hi + 131072; dlo = dw_lo + 131072; base = q - 1703936; }
  const size_t i = (size_t)base * 4;
  split_store4h(*(const float4*)&src[i], dhi, dlo, i);
}

// Reduce 2 out_proj split-K slabs -> final output.
__global__ __launch_bounds__(256) void reduce_out(const float* __restrict__ p,
                                                  float* __restrict__ o, int n) {
  const int i = (blockIdx.x * 256 + threadIdx.x) * 4;
  if (i >= n) return;
  float4 a = *(const float4*)&p[i];
  float4 b = *(const float4*)&p[(size_t)n + i];
  *(float4*)&o[i] = make_float4(a.x + b.x, a.y + b.y, a.z + b.z, a.w + b.w);
}

// =====================================================================
// Conv (w=4, causal) + bias + SiLU -> transposed f16 hi/lo planes (l,d).
// Also: silu(z) transposed to (l,d) interleaved ushort2 plane.
// =====================================================================
__global__ __launch_bounds__(256) void conv_tr_kernel(const float* __restrict__ xz,
                                                      const float* __restrict__ cw,
                                                      const float* __restrict__ cb,
                                                      ushort* __restrict__ xcT_hi,
                                                      ushort* __restrict__ xcT_lo,
                                                      ushort2* __restrict__ zs) {
  const int l0 = blockIdx.x * 64, d0 = blockIdx.y * 64;
  const int tid = threadIdx.x;
  __shared__ float xin[64][68];  // cols 0..66 = l0-3 .. l0+63
  __shared__ float To[64][65];
  __shared__ float cwS[64][4];
  __shared__ float cbS[64];

  for (int i = tid; i < 1024; i += 256) {
    const int d = i >> 4, q = i & 15;
    float4 v = *(const float4*)&xz[(size_t)(d0 + d) * SEQ + l0 + q * 4];
    xin[d][3 + q * 4 + 0] = v.x; xin[d][3 + q * 4 + 1] = v.y;
    xin[d][3 + q * 4 + 2] = v.z; xin[d][3 + q * 4 + 3] = v.w;
  }
  if (tid < 192) {
    const int j = tid >> 6, d = tid & 63;
    const int l = l0 - 3 + j;
    xin[d][j] = (l >= 0) ? xz[(size_t)(d0 + d) * SEQ + l] : 0.f;
  }
  if (tid < 64) {
    cbS[tid] = cb[d0 + tid];
    float4 w = *(const float4*)&cw[(d0 + tid) * 4];
    cwS[tid][0] = w.x; cwS[tid][1] = w.y; cwS[tid][2] = w.z; cwS[tid][3] = w.w;
  }
  __syncthreads();

  for (int i = tid; i < 4096; i += 256) {
    const int d = i >> 6, l = i & 63;
    float a = cbS[d] + cwS[d][0] * xin[d][l] + cwS[d][1] * xin[d][l + 1] +
              cwS[d][2] * xin[d][l + 2] + cwS[d][3] * xin[d][l + 3];
    To[d][l] = a / (1.f + __expf(-a));
  }
  __syncthreads();

  for (int i = tid; i < 4096; i += 256) {
    const int l = i >> 6, dd = i & 63;
    float v = To[dd][l];  // stride-65: conflict-free
    ushort h = f2h(v);
    xcT_hi[(size_t)(l0 + l) * DIN + d0 + dd] = h;
    xcT_lo[(size_t)(l0 + l) * DIN + d0 + dd] = f2h((v - h2f(h)) * 2048.f);
  }
  __syncthreads();  // To fully consumed; reuse for z tile

  for (int i = tid; i < 1024; i += 256) {
    const int d = i >> 4, q = i & 15;
    float4 v = *(const float4*)&xz[(size_t)(DIN + d0 + d) * SEQ + l0 + q * 4];
    To[d][q * 4 + 0] = v.x / (1.f + __expf(-v.x));
    To[d][q * 4 + 1] = v.y / (1.f + __expf(-v.y));
    To[d][q * 4 + 2] = v.z / (1.f + __expf(-v.z));
    To[d][q * 4 + 3] = v.w / (1.f + __expf(-v.w));
  }
  __syncthreads();
  for (int i = tid; i < 4096; i += 256) {
    const int l = i >> 6, dd = i & 63;
    zs[(size_t)(l0 + l) * DIN + d0 + dd] = split2(To[dd][l]);
  }
}

// Reduce 16 x_proj split-K slabs (SEQ x 192, l-major) -> B/C tables +
// dt rows as (l,r) f16 hi/lo planes.
__global__ __launch_bounds__(256) void reduce_dblT_kernel(const float* __restrict__ p,
                                                          float* __restrict__ BT1,
                                                          float* __restrict__ CT1,
                                                          float* __restrict__ BT2,
                                                          float* __restrict__ CT2,
                                                          ushort* __restrict__ dtT_hi,
                                                          ushort* __restrict__ dtT_lo) {
  const int NE = SEQ * 192;
  const int idx = blockIdx.x * 256 + threadIdx.x;
  float s = 0.f;
#pragma unroll
  for (int cc = 0; cc < 16; ++cc) s += p[(size_t)cc * NE + idx];
  const int l = idx / 192, k = idx - l * 192;
  if (k < 64) {
    const size_t off = (size_t)l * 64 + k;
    const ushort hh = f2h(s);
    dtT_hi[off] = hh; dtT_lo[off] = f2h((s - h2f(hh)) * 2048.f);
  } else if (k < 80)  BT1[l * NST + (k - 64)] = s;
  else if (k < 96)    CT1[l * NST + (k - 80)] = s;
  else if (k < 160) {
    const size_t off = 131072 + (size_t)l * 64 + (k - 96);
    const ushort hh = f2h(s);
    dtT_hi[off] = hh; dtT_lo[off] = f2h((s - h2f(hh)) * 2048.f);
  }
  else if (k < 176)   BT2[l * NST + (k - 160)] = s;
  else                CT2[l * NST + (k - 176)] = s;
}

// =====================================================================
// Chunked selective scan, BOTH branches fused per thread (u/sp read once).
// sp as interleaved ushort2; u as separate hi/lo planes (GEMM needs them).
// =====================================================================
__global__ __launch_bounds__(256) void scan_phase_a(const ushort* __restrict__ uhi,
                                                    const ushort* __restrict__ ulo,
                                                    const ushort2* __restrict__ sp1,
                                                    const ushort2* __restrict__ sp2,
                                                    const float* __restrict__ BT1,
                                                    const float* __restrict__ BT2,
                                                    const float* __restrict__ Al1,
                                                    const float* __restrict__ Al2,
                                                    float* __restrict__ hend,
                                                    float* __restrict__ Pend) {
  const int c = blockIdx.y, t0 = c * CH;
  const int d = blockIdx.x * 256 + threadIdx.x;
  const size_t gbase = (size_t)t0 * DIN + d;

  __shared__ __align__(16) float Bs[2][CH][NST];
  {
    const int j = threadIdx.x;  // 2*CH*NST floats = 256 float4
    if (j < 128) ((float4*)&Bs[0][0][0])[j] = ((const float4*)&BT1[(size_t)t0 * NST])[j];
    else ((float4*)&Bs[1][0][0])[j - 128] = ((const float4*)&BT2[(size_t)t0 * NST])[j - 128];
  }
  __syncthreads();

  bool fast = true;
#pragma unroll
  for (int n = 0; n < NST; ++n) {
    float k1 = __expf(Al1[(size_t)d * NST + n]);
    float k2 = __expf(Al2[(size_t)d * NST + n]);
    fast = fast && (fabsf(k1 - (float)(n + 1)) < 1e-3f) && (fabsf(k2 - (float)(n + 1)) < 1e-3f);
  }
  float h1[NST], h2[NST];
#pragma unroll
  for (int n = 0; n < NST; ++n) { h1[n] = 0.f; h2[n] = 0.f; }
  float S1 = 0.f, S2 = 0.f;

  if (fast) {
    for (int tt = 0; tt < CH / 4; ++tt) {
      float s1[4], s2[4], ua[4];
#pragma unroll
      for (int j = 0; j < 4; ++j) {
        const size_t idx = gbase + (size_t)(tt * 4 + j) * DIN;
        s1[j] = join2(sp1[idx]);
        s2[j] = join2(sp2[idx]);
        ua[j] = h2f(uhi[idx]) + h2f(ulo[idx]) * (1.f / 2048.f);
      }
#pragma unroll
      for (int j = 0; j < 4; ++j) {
        const int t = tt * 4 + j;
        S1 += s1[j]; S2 += s2[j];
        const float spu1 = s1[j] * ua[j], spu2 = s2[j] * ua[j];
        float p[NST];
        powers16(__expf(-s1[j]), p);
#pragma unroll
        for (int n = 0; n < NST; ++n) h1[n] = fmaf(p[n], h1[n], spu1 * Bs[0][t][n]);
        powers16(__expf(-s2[j]), p);
#pragma unroll
        for (int n = 0; n < NST; ++n) h2[n] = fmaf(p[n], h2[n], spu2 * Bs[1][t][n]);
      }
    }
  } else {
    float A1e[NST], A2e[NST];
#pragma unroll
    for (int n = 0; n < NST; ++n) {
      A1e[n] = -__expf(Al1[(size_t)d * NST + n]) * LOG2E;
      A2e[n] = -__expf(Al2[(size_t)d * NST + n]) * LOG2E;
    }
    for (int tt = 0; tt < CH / 4; ++tt) {
      float s1[4], s2[4], ua[4];
#pragma unroll
      for (int j = 0; j < 4; ++j) {
        const size_t idx = gbase + (size_t)(tt * 4 + j) * DIN;
        s1[j] = join2(sp1[idx]);
        s2[j] = join2(sp2[idx]);
        ua[j] = h2f(uhi[idx]) + h2f(ulo[idx]) * (1.f / 2048.f);
      }
#pragma unroll
      for (int j = 0; j < 4; ++j) {
        const int t = tt * 4 + j;
        S1 += s1[j]; S2 += s2[j];
        const float spu1 = s1[j] * ua[j], spu2 = s2[j] * ua[j];
#pragma unroll
        for (int n = 0; n < NST; ++n) {
          h1[n] = fmaf(exp2f(A1e[n] * s1[j]), h1[n], spu1 * Bs[0][t][n]);
          h2[n] = fmaf(exp2f(A2e[n] * s2[j]), h2[n], spu2 * Bs[1][t][n]);
        }
      }
    }
  }

  float P1[NST], P2[NST];
  if (fast) {
    powers16(__expf(-S1), P1);
    powers16(__expf(-S2), P2);
  } else {
#pragma unroll
    for (int n = 0; n < NST; ++n) {
      P1[n] = exp2f(-__expf(Al1[(size_t)d * NST + n]) * LOG2E * S1);
      P2[n] = exp2f(-__expf(Al2[(size_t)d * NST + n]) * LOG2E * S2);
    }
  }
  const size_t b1 = ((size_t)c * DIN + d) * NST;
  const size_t b2 = ((size_t)(NCH + c) * DIN + d) * NST;
#pragma unroll
  for (int n = 0; n < NST; n += 4) {
    *(float4*)&hend[b1 + n] = make_float4(h1[n], h1[n + 1], h1[n + 2], h1[n + 3]);
    *(float4*)&Pend[b1 + n] = make_float4(P1[n], P1[n + 1], P1[n + 2], P1[n + 3]);
    *(float4*)&hend[b2 + n] = make_float4(h2[n], h2[n + 1], h2[n + 2], h2[n + 3]);
    *(float4*)&Pend[b2 + n] = make_float4(P2[n], P2[n + 1], P2[n + 2], P2[n + 3]);
  }
}

// Merged: blocks [0,256) do the chunk-carry (hin overwrites Pend in place);
// blocks [256,2304) convert outw -> f16 hi plane.
__global__ __launch_bounds__(256) void carry_cvt(const float* __restrict__ hend,
                                                 float* __restrict__ PendHin,
                                                 const float* __restrict__ outw,
                                                 ushort* __restrict__ ow_hi) {
  const int b = blockIdx.x;
  if (b < 256) {
    const int flat = b * 256 + threadIdx.x;
    const int br = flat >> 15;
    const int dn = flat & 32767;
    float h = 0.f;
    for (int c = 0; c < NCH; ++c) {
      size_t idx = ((size_t)(br * NCH + c) << 15) + dn;
      float Pv = PendHin[idx];
      float he = hend[idx];
      PendHin[idx] = h;
      h = fmaf(Pv, h, he);
    }
  } else {
    const size_t i = ((size_t)(b - 256) * 256 + threadIdx.x) * 4;  // < 2,097,152
    float4 v = *(const float4*)&outw[i];
    *(ushort4*)&ow_hi[i] = make_ushort4(f2h(v.x), f2h(v.y), f2h(v.z), f2h(v.w));
  }
}

// Phase C fused: both branches per thread; emits yd = (y1-y2+(D1-D2)u)*silu(z)
// directly as f16 hi/lo planes IN PLACE over the u planes.
__global__ __launch_bounds__(256) void scan_phase_c(const ushort* __restrict__ uhi,
                                                    const ushort* __restrict__ ulo,
                                                    const ushort2* __restrict__ sp1,
                                                    const ushort2* __restrict__ sp2,
                                                    const float* __restrict__ BT1,
                                                    const float* __restrict__ CT1,
                                                    const float* __restrict__ BT2,
                                                    const float* __restrict__ CT2,
                                                    const float* __restrict__ Al1,
                                                    const float* __restrict__ Al2,
                                                    const float* __restrict__ D1,
                                                    const float* __restrict__ D2,
                                                    const float* __restrict__ hin,
                                                    const ushort2* __restrict__ zs,
                                                    ushort* __restrict__ yd_hi,
                                                    ushort* __restrict__ yd_lo) {
  const int c = blockIdx.y, t0 = c * CH;
  const int d = blockIdx.x * 256 + threadIdx.x;
  const size_t gbase = (size_t)t0 * DIN + d;

  __shared__ __align__(16) float Bs[2][CH][NST];
  __shared__ __align__(16) float Cs[2][CH][NST];
  {
    const int j = threadIdx.x;
    if (j < 128) {
      ((float4*)&Bs[0][0][0])[j] = ((const float4*)&BT1[(size_t)t0 * NST])[j];
      ((float4*)&Cs[0][0][0])[j] = ((const float4*)&CT1[(size_t)t0 * NST])[j];
    } else {
      ((float4*)&Bs[1][0][0])[j - 128] = ((const float4*)&BT2[(size_t)t0 * NST])[j - 128];
      ((float4*)&Cs[1][0][0])[j - 128] = ((const float4*)&CT2[(size_t)t0 * NST])[j - 128];
    }
  }
  __syncthreads();

  bool fast = true;
#pragma unroll
  for (int n = 0; n < NST; ++n) {
    float k1 = __expf(Al1[(size_t)d * NST + n]);
    float k2 = __expf(Al2[(size_t)d * NST + n]);
    fast = fast && (fabsf(k1 - (float)(n + 1)) < 1e-3f) && (fabsf(k2 - (float)(n + 1)) < 1e-3f);
  }
  const float Ddd = D1[d] - D2[d];
  float h1[NST], h2[NST];
  const size_t hb1 = ((size_t)c * DIN + d) * NST;
  const size_t hb2 = ((size_t)(NCH + c) * DIN + d) * NST;
#pragma unroll
  for (int n = 0; n < NST; n += 4) {
    float4 v1 = *(const float4*)&hin[hb1 + n];
    h1[n] = v1.x; h1[n + 1] = v1.y; h1[n + 2] = v1.z; h1[n + 3] = v1.w;
    float4 v2 = *(const float4*)&hin[hb2 + n];
    h2[n] = v2.x; h2[n + 1] = v2.y; h2[n + 2] = v2.z; h2[n + 3] = v2.w;
  }

  if (fast) {
    for (int tt = 0; tt < CH / 4; ++tt) {
      float s1[4], s2[4], ua[4];
#pragma unroll
      for (int j = 0; j < 4; ++j) {
        const size_t idx = gbase + (size_t)(tt * 4 + j) * DIN;
        s1[j] = join2(sp1[idx]);
        s2[j] = join2(sp2[idx]);
        ua[j] = h2f(uhi[idx]) + h2f(ulo[idx]) * (1.f / 2048.f);
      }
#pragma unroll
      for (int j = 0; j < 4; ++j) {
        const int t = tt * 4 + j;
        const size_t idx = gbase + (size_t)t * DIN;
        const float spu1 = s1[j] * ua[j], spu2 = s2[j] * ua[j];
        float p[NST];
        float y1 = 0.f, y2 = 0.f;
        powers16(__expf(-s1[j]), p);
#pragma unroll
        for (int n = 0; n < NST; ++n) {
          h1[n] = fmaf(p[n], h1[n], spu1 * Bs[0][t][n]);
          y1 = fmaf(h1[n], Cs[0][t][n], y1);
        }
        powers16(__expf(-s2[j]), p);
#pragma unroll
        for (int n = 0; n < NST; ++n) {
          h2[n] = fmaf(p[n], h2[n], spu2 * Bs[1][t][n]);
          y2 = fmaf(h2[n], Cs[1][t][n], y2);
        }
        const float zv = join2(zs[idx]);
        const float yd = (y1 - y2 + Ddd * ua[j]) * zv;
        const ushort hh = f2h(yd);
        yd_hi[idx] = hh;
        yd_lo[idx] = f2h((yd - h2f(hh)) * 2048.f);
      }
    }
  } else {
    float A1e[NST], A2e[NST];
#pragma unroll
    for (int n = 0; n < NST; ++n) {
      A1e[n] = -__expf(Al1[(size_t)d * NST + n]) * LOG2E;
      A2e[n] = -__expf(Al2[(size_t)d * NST + n]) * LOG2E;
    }
    for (int tt = 0; tt < CH / 4; ++tt) {
      float s1[4], s2[4], ua[4];
#pragma unroll
      for (int j = 0; j < 4; ++j) {
        const size_t idx = gbase + (size_t)(tt * 4 + j) * DIN;
        s1[j] = join2(sp1[idx]);
        s2[j] = join2(sp2[idx]);
        ua[j] = h2f(uhi[idx]) + h2f(ulo[idx]) * (1.f / 2048.f);
      }
#pragma unroll
      for (int j = 0; j < 4; ++j) {
        const int t = tt * 4 + j;
        const size_t idx = gbase + (size_t)t * DIN;
        const float spu1 = s1[j] * ua[j], spu2 = s2[j] * ua[j];
        float y1 = 0.f, y2 = 0.f;
#pragma unroll
        for (int n = 0; n < NST; ++n) {
          h1[n] = fmaf(exp2f(A1e[n] * s1[j]), h1[n], spu1 * Bs[0][t][n]);
          y1 = fmaf(h1[n], Cs[0][t][n], y1);
          h2[n] = fmaf(exp2f(A2e[n] * s2[j]), h2[n], spu2 * Bs[1][t][n]);
          y2 = fmaf(h2[n], Cs[1][t][n], y2);
        }
        const float zv = join2(zs[idx]);
        const float yd = (y1 - y2 + Ddd * ua[j]) * zv;
        const ushort hh = f2h(yd);
        yd_hi[idx] = hh;
        yd_lo[idx] = f2h((yd - h2f(hh)) * 2048.f);
      }
    }
  }
}

// =====================================================================
extern "C" void kernel_launch(void* const* d_in, const int* in_sizes, int n_in,
                              void* d_out, int out_size, void* d_ws, size_t ws_size,
                              hipStream_t stream) {
  const float* hidden = (const float*)d_in[0];
  const float* in_proj_w = (const float*)d_in[1];
  const float* conv_w = (const float*)d_in[2];
  const float* conv_b = (const float*)d_in[3];
  const float* x1w = (const float*)d_in[4];
  const float* dtw1 = (const float*)d_in[5];
  const float* dtb1 = (const float*)d_in[6];
  const float* Al1 = (const float*)d_in[7];
  const float* D1 = (const float*)d_in[8];
  const float* x2w = (const float*)d_in[9];
  const float* dtw2 = (const float*)d_in[10];
  const float* dtb2 = (const float*)d_in[11];
  const float* Al2 = (const float*)d_in[12];
  const float* D2 = (const float*)d_in[13];
  const float* outw = (const float*)d_in[14];
  float* out = (float*)d_out;

  // Workspace layout (floats), same 34.47M footprint.
  float* ws = (float*)d_ws;
  float* xz = ws;                                    // 8.39M  (x rows, z rows)
  float* xcTbuf = xz + (size_t)4096 * SEQ;           // 4.19M  u f16 hi/lo planes
  float* dtTbuf = xcTbuf + (size_t)SEQ * DIN;        // 393K   dtT f16 hi/lo planes
  float* spbuf1 = dtTbuf + (size_t)192 * SEQ;        // 4.19M  sp1 ushort2 plane
  float* spbuf2 = spbuf1 + (size_t)SEQ * DIN;        // 4.19M  sp2 ushort2 plane
  float* zsbuf = spbuf2 + (size_t)SEQ * DIN;         // 4.19M  silu(z) ushort2 plane
  float* hendB = zsbuf + (size_t)SEQ * DIN;          // 4.19M
  float* PendB = hendB + (size_t)2 * NCH * DIN * NST;// 4.19M
  float* BT1 = PendB + (size_t)2 * NCH * DIN * NST;  // 32K each
  float* CT1 = BT1 + (size_t)SEQ * NST;
  float* BT2 = CT1 + (size_t)SEQ * NST;
  float* CT2 = BT2 + (size_t)SEQ * NST;
  float* wxp = CT2 + (size_t)SEQ * NST;              // 393K stacked x_proj W planes

  // Aliases (lifetime-disjoint):
  ushort* xcT_hi = (ushort*)xcTbuf;                  // u planes, steps 3..scan C
  ushort* xcT_lo = (ushort*)(xcTbuf + 2097152);
  ushort* dtT_hi = (ushort*)dtTbuf;                  // dt rows (l,64) x 2 branches
  ushort* dtT_lo = dtT_hi + 262144;
  ushort2* sp1 = (ushort2*)spbuf1;                   // interleaved sp planes
  ushort2* sp2 = (ushort2*)spbuf2;
  ushort2* zs = (ushort2*)zsbuf;                     // interleaved silu(z) plane
  ushort* w_hi = (ushort*)zsbuf;                     // in_proj_w planes (dead after step 2,
  ushort* w_lo = (ushort*)(zsbuf + 2097152);         //   before conv writes zs plane)
  ushort* h_hi = (ushort*)hendB;                     // hidden hi plane (dead after step 2)
  ushort* dw_hi = ((ushort*)hendB) + 2097152;        // dtw planes behind h_hi (dead
  ushort* dw_lo = dw_hi + 262144;                    //   before scan_a writes hendB)
  ushort* wx_hi = (ushort*)wxp;                      // stacked x_proj weights 192x2048
  ushort* wx_lo = (ushort*)(wxp + 196608);
  float* xp_part = spbuf1;                           // 16 slabs x SEQ*192*4B = 25.2MB,
                                                     //   spans spbuf1+spbuf2 (sp written later)
  ushort* yd_hi = (ushort*)xcTbuf;                   // yd planes overwrite u in-place
  ushort* yd_lo = (ushort*)(xcTbuf + 2097152);
  ushort* ow_hi = (ushort*)xz;                       // outw hi plane in dead xz
  float* opart = spbuf1;                             // out_proj partials: 2 x 8.4MB = 16.8MB

  dim3 blk(256);

  // 1) fused split-convert: in_proj_w, hidden (hi only), x1w, x2w, dtw1, dtw2
  cvt_fused<<<dim3(6784), blk, 0, stream>>>(in_proj_w, hidden, x1w, x2w, dtw1, dtw2,
                                            w_hi, w_lo, h_hi, wx_hi, wx_lo, dw_hi, dw_lo);

  // 2) in_proj via f16 MFMA 2-pass (dual-32 stages) -> xz (e,l)
  gemm3p<128, 128, 1, 2><<<dim3(SEQ / 128, 4096 / 128, 1), blk, 0, stream>>>(
      w_hi, w_lo, h_hi, h_hi, xz, 4096, SEQ, DMODEL);

  // 3) conv + silu -> u f16 planes (l,d); silu(z) -> ushort2 plane (l,d)
  conv_tr_kernel<<<dim3(SEQ / 64, DIN / 64), blk, 0, stream>>>(
      xz, conv_w, conv_b, xcT_hi, xcT_lo, zs);

  // 4) x_proj swapped: C[l, k(192)] = sum_d xcT[l,d]*wx[k,d], split-K=16
  gemm3p<128, 64, 16, 0><<<dim3(192 / 64, SEQ / 128, 16), blk, 0, stream>>>(
      xcT_hi, xcT_lo, wx_hi, wx_lo, xp_part, SEQ, 192, DIN);

  // 5) reduce 16 slabs -> B/C tables + dtT f16 planes
  reduce_dblT_kernel<<<dim3(192 * SEQ / 256), blk, 0, stream>>>(
      xp_part, BT1, CT1, BT2, CT2, dtT_hi, dtT_lo);

  // 6) dt projection on MFMA (swapped operands, 16B-store epilogue)
  dt_mfma<<<dim3(SEQ / 128, DIN / 128, 2), blk, 0, stream>>>(
      dtT_hi, dtT_lo, dw_hi, dw_lo, dtb1, dtb2, sp1, sp2);

  // 7) chunked scan (A, carry+cvt, C)
  scan_phase_a<<<dim3(DIN / 256, NCH), blk, 0, stream>>>(
      xcT_hi, xcT_lo, sp1, sp2, BT1, BT2, Al1, Al2, hendB, PendB);
  carry_cvt<<<dim3(2304), blk, 0, stream>>>(hendB, PendB, outw, ow_hi);
  scan_phase_c<<<dim3(DIN / 256, NCH), blk, 0, stream>>>(
      xcT_hi, xcT_lo, sp1, sp2, BT1, CT1, BT2, CT2, Al1, Al2,
      D1, D2, PendB, zs, yd_hi, yd_lo);

  // 8) out_proj via f16 MFMA 2-pass, BM=64 / split-K=2 (512 blocks kept,
  //    partial traffic halved: 2 slabs x 8.4MB instead of 4 x 8.4MB)
  gemm3p<64, 128, 2, 2><<<dim3(DMODEL / 128, SEQ / 64, 2), blk, 0, stream>>>(
      yd_hi, yd_lo, ow_hi, ow_hi, opart, SEQ, DMODEL, DIN);
  reduce_out<<<dim3(SEQ * DMODEL / 1024), blk, 0, stream>>>(opart, out, SEQ * DMODEL);
}